// Round 7
// baseline (459.624 us; speedup 1.0000x reference)
//
#include <hip/hip_runtime.h>
#include <math.h>

#define B_ 16
#define T_ 1024
#define D_ 96
#define L_ 6
#define NH_ 6
#define HS_ 16
#define FF_ 384

typedef _Float16 h4 __attribute__((ext_vector_type(4)));
typedef float f4 __attribute__((ext_vector_type(4)));

#define MFMA16 __builtin_amdgcn_mfma_f32_16x16x16f16

// packed f16 W^T buffer segment offsets (in halves)
#define OFF_GO   0
#define OFF_QKV  9216
#define OFF_PROJ 175104
#define OFF_FF1  230400
#define OFF_FF2  451584
#define OFF_ACT  672768
#define PACK_TOTAL 674304

// Q weights pre-scaled by 1/sqrt(16) * log2(e) so attn uses exp2 directly.
#define QSCALE 0.3606737602222409f

// ---------- pack all weights -> f16 W^T [N][K] ----------
__global__ __launch_bounds__(256) void pack_all_kernel(
    const float* __restrict__ w_go, const float* __restrict__ wq,
    const float* __restrict__ wk, const float* __restrict__ wv,
    const float* __restrict__ w_proj, const float* __restrict__ w_ff1,
    const float* __restrict__ w_ff2, const float* __restrict__ w_act,
    _Float16* __restrict__ P) {
  int i = blockIdx.x * 256 + threadIdx.x;
  if (i >= PACK_TOTAL) return;
  float v;
  if (i < OFF_QKV) {                       // w_go [96k][96n] -> [n][k]
    int o = i, n = o / 96, k = o % 96;
    v = w_go[k * 96 + n];
  } else if (i < OFF_PROJ) {               // wq/wk/wv -> [l][c=288][d=96]
    int o = i - OFF_QKV;
    int l = o / 27648, r = o % 27648, c = r / 96, d = r % 96;
    int which = c / 96;
    int hc = c % 96, h = hc >> 4, j = hc & 15;
    const float* s = (which == 0) ? wq : (which == 1 ? wk : wv);
    v = s[((l * NH_ + h) * 96 + d) * 16 + j];
    if (which == 0) v *= QSCALE;
  } else if (i < OFF_FF1) {                // w_proj [l][96k][96n] -> [l][n][k]
    int o = i - OFF_PROJ;
    int l = o / 9216, r = o % 9216, n = r / 96, k = r % 96;
    v = w_proj[l * 9216 + k * 96 + n];
  } else if (i < OFF_FF2) {                // w_ff1 [l][96k][384n] -> [l][n][k]
    int o = i - OFF_FF1;
    int l = o / 36864, r = o % 36864, n = r / 96, k = r % 96;
    v = w_ff1[l * 36864 + k * 384 + n];
  } else if (i < OFF_ACT) {                // w_ff2 [l][384k][96n] -> [l][n][k]
    int o = i - OFF_FF2;
    int l = o / 36864, r = o % 36864, n = r / 384, k = r % 384;
    v = w_ff2[l * 36864 + k * 96 + n];
  } else {                                 // w_act [96k][16n] -> [n][k]
    int o = i - OFF_ACT;
    int n = o / 96, k = o % 96;
    v = w_act[k * 16 + n];
  }
  P[i] = (_Float16)v;
}

// ---------- fused stage kernel, 3 waves cooperate on 16 tokens ----------
// wave w owns col-frags {2w, 2w+1}; ff1 hidden frags 8w..8w+7;
// tail frags 6w..6w+5 (w0=Q, w1=K, w2=V). LDS exchanges between phases.
// Weight loads are register-batched / 2-deep pipelined to hide L2 latency.
template <bool EMBED, bool HEAD>
__global__ __launch_bounds__(192, 3) void stage_kernel(
    const float* __restrict__ goals, const float* __restrict__ obss,
    const float* __restrict__ pos, const float* __restrict__ b_go,
    const _Float16* __restrict__ obh, const _Float16* __restrict__ Wp,
    const float* __restrict__ bp, float* __restrict__ x,
    const _Float16* __restrict__ W1, const float* __restrict__ b1,
    const _Float16* __restrict__ W2, const float* __restrict__ b2,
    const float* __restrict__ ln2g, const float* __restrict__ ln2b,
    const float* __restrict__ lntg, const float* __restrict__ lntb,
    const _Float16* __restrict__ Wtail, const float* __restrict__ btail,
    _Float16* __restrict__ qh, _Float16* __restrict__ kh,
    _Float16* __restrict__ vt, float* __restrict__ out) {
  __shared__ _Float16 xsh[6 * 16 * 16];        // xn exchange (h4 frags)
  __shared__ float ysh[3 * 6 * 16 * 20];       // ff2 partials, stride 20 pad
  __shared__ float lnsh[2][3][16][2];          // LN partial (s, sq)
  int tid = threadIdx.x;
  int wave = tid / 64, lane = tid & 63;
  int lr = lane & 15, lg = lane >> 4;
  int row0 = blockIdx.x * 16;
  int token = row0 + lr;
  int bidx = token >> 10, t = token & 1023;
  int c0 = wave * 2;
  const f4 zero4 = {0.f, 0.f, 0.f, 0.f};

  f4 xc[2];  // own 2 col-frag chunks of the residual value
  if constexpr (EMBED) {
    // batch: inputs + all proj weights, then MFMA
    h4 ef[6];
#pragma unroll
    for (int st = 0; st < 6; ++st) {
      int k0 = st * 16 + lg * 4;
      f4 s4;
      if (st < 2) s4 = *(const f4*)(goals + bidx * 32 + k0);
      else        s4 = *(const f4*)(obss + (size_t)(bidx * 1024 + t) * 64 + (k0 - 32));
      ef[st] = (h4){(_Float16)s4[0], (_Float16)s4[1], (_Float16)s4[2], (_Float16)s4[3]};
    }
    h4 wpreg[2][6];
#pragma unroll
    for (int i = 0; i < 2; ++i) {
      const _Float16* wrow = Wp + (size_t)((c0 + i) * 16 + lr) * 96 + lg * 4;
#pragma unroll
      for (int st = 0; st < 6; ++st) wpreg[i][st] = *(const h4*)(wrow + st * 16);
    }
    f4 pp[2], bb[2];
#pragma unroll
    for (int i = 0; i < 2; ++i) {
      bb[i] = *(const f4*)(b_go + (c0 + i) * 16 + lg * 4);
      pp[i] = *(const f4*)(pos + (size_t)t * 96 + (c0 + i) * 16 + lg * 4);
    }
#pragma unroll
    for (int i = 0; i < 2; ++i) {
      f4 a = zero4;
#pragma unroll
      for (int st = 0; st < 6; ++st)
        a = MFMA16(wpreg[i][st], ef[st], a, 0, 0, 0);
#pragma unroll
      for (int j = 0; j < 4; ++j) xc[i][j] = a[j] + bb[i][j] + pp[i][j];
      *(f4*)(x + (size_t)token * 96 + (c0 + i) * 16 + lg * 4) = xc[i];
    }
  } else {
    // ---- proj + resid: batch all loads, then MFMA ----
    h4 obf[6];
    const _Float16* orow = obh + (size_t)token * 96 + lg * 4;
#pragma unroll
    for (int st = 0; st < 6; ++st) obf[st] = *(const h4*)(orow + st * 16);
    h4 wpreg[2][6];
#pragma unroll
    for (int i = 0; i < 2; ++i) {
      const _Float16* wrow = Wp + (size_t)((c0 + i) * 16 + lr) * 96 + lg * 4;
#pragma unroll
      for (int st = 0; st < 6; ++st) wpreg[i][st] = *(const h4*)(wrow + st * 16);
    }
    f4 xr[2], bb[2];
#pragma unroll
    for (int i = 0; i < 2; ++i) {
      xr[i] = *(const f4*)(x + (size_t)token * 96 + (c0 + i) * 16 + lg * 4);
      bb[i] = *(const f4*)(bp + (c0 + i) * 16 + lg * 4);
    }
    f4 x1[2];
#pragma unroll
    for (int i = 0; i < 2; ++i) {
      f4 a = zero4;
#pragma unroll
      for (int st = 0; st < 6; ++st)
        a = MFMA16(wpreg[i][st], obf[st], a, 0, 0, 0);
#pragma unroll
      for (int j = 0; j < 4; ++j) x1[i][j] = a[j] + bb[i][j] + xr[i][j];
    }
    // ---- LN2: cross-wave stats via LDS ----
    {
      float s = 0.f, sq = 0.f;
#pragma unroll
      for (int i = 0; i < 2; ++i)
#pragma unroll
        for (int j = 0; j < 4; ++j) { s += x1[i][j]; sq += x1[i][j] * x1[i][j]; }
      s += __shfl_xor(s, 16); sq += __shfl_xor(sq, 16);
      s += __shfl_xor(s, 32); sq += __shfl_xor(sq, 32);
      if (lane < 16) { lnsh[0][wave][lr][0] = s; lnsh[0][wave][lr][1] = sq; }
    }
    __syncthreads();
    {
      float s = lnsh[0][0][lr][0] + lnsh[0][1][lr][0] + lnsh[0][2][lr][0];
      float sq = lnsh[0][0][lr][1] + lnsh[0][1][lr][1] + lnsh[0][2][lr][1];
      float mean = s * (1.f / 96.f);
      float rs = rsqrtf(sq * (1.f / 96.f) - mean * mean + 1e-5f);
#pragma unroll
      for (int i = 0; i < 2; ++i) {
        int cf = c0 + i;
        f4 g4 = *(const f4*)(ln2g + cf * 16 + lg * 4);
        f4 b4 = *(const f4*)(ln2b + cf * 16 + lg * 4);
        h4 xn;
#pragma unroll
        for (int j = 0; j < 4; ++j)
          xn[j] = (_Float16)((x1[i][j] - mean) * rs * g4[j] + b4[j]);
        *(h4*)&xsh[(cf * 16 + lr) * 16 + lg * 4] = xn;
      }
    }
    __syncthreads();
    h4 xnf[6];
#pragma unroll
    for (int cf = 0; cf < 6; ++cf)
      xnf[cf] = *(const h4*)&xsh[(cf * 16 + lr) * 16 + lg * 4];

    // ---- ff1 + relu (own 8 hidden frags), 2-deep weight pipeline ----
    int nf0 = wave * 8;
    h4 hf[8];
    {
      h4 wcur[6], wnxt[6];
      const _Float16* wr0 = W1 + (size_t)(nf0 * 16 + lr) * 96 + lg * 4;
#pragma unroll
      for (int st = 0; st < 6; ++st) wcur[st] = *(const h4*)(wr0 + st * 16);
#pragma unroll
      for (int f = 0; f < 8; ++f) {
        if (f < 7) {
          const _Float16* wr = W1 + (size_t)((nf0 + f + 1) * 16 + lr) * 96 + lg * 4;
#pragma unroll
          for (int st = 0; st < 6; ++st) wnxt[st] = *(const h4*)(wr + st * 16);
        }
        f4 h = zero4;
#pragma unroll
        for (int st = 0; st < 6; ++st)
          h = MFMA16(wcur[st], xnf[st], h, 0, 0, 0);
        f4 b4 = *(const f4*)(b1 + (nf0 + f) * 16 + lg * 4);
#pragma unroll
        for (int j = 0; j < 4; ++j)
          hf[f][j] = (_Float16)fmaxf(h[j] + b4[j], 0.f);
#pragma unroll
        for (int st = 0; st < 6; ++st) wcur[st] = wnxt[st];
      }
    }

    // ---- ff2: K-split partials (2-deep weight pipeline), LDS reduce ----
    f4 yown[2];
    {
      h4 wcur[8], wnxt[8];
      const _Float16* wr0 = W2 + (size_t)(0 * 16 + lr) * 384 + nf0 * 16 + lg * 4;
#pragma unroll
      for (int f = 0; f < 8; ++f) wcur[f] = *(const h4*)(wr0 + f * 16);
#pragma unroll
      for (int mf = 0; mf < 6; ++mf) {
        if (mf < 5) {
          const _Float16* wr = W2 + (size_t)((mf + 1) * 16 + lr) * 384 + nf0 * 16 + lg * 4;
#pragma unroll
          for (int f = 0; f < 8; ++f) wnxt[f] = *(const h4*)(wr + f * 16);
        }
        f4 y = zero4;
#pragma unroll
        for (int f = 0; f < 8; ++f)
          y = MFMA16(wcur[f], hf[f], y, 0, 0, 0);
        if ((mf >> 1) == wave) yown[mf & 1] = y;
        else *(f4*)&ysh[((wave * 6 + mf) * 16 + lr) * 20 + lg * 4] = y;
#pragma unroll
        for (int f = 0; f < 8; ++f) wcur[f] = wnxt[f];
      }
    }
    __syncthreads();
#pragma unroll
    for (int i = 0; i < 2; ++i) {
      int mf = c0 + i;
      f4 tot = yown[i];
#pragma unroll
      for (int ow = 0; ow < 3; ++ow)
        if (ow != wave)
          tot += *(const f4*)&ysh[((ow * 6 + mf) * 16 + lr) * 20 + lg * 4];
      f4 b4 = *(const f4*)(b2 + mf * 16 + lg * 4);
#pragma unroll
      for (int j = 0; j < 4; ++j) xc[i][j] = x1[i][j] + tot[j] + b4[j];
      if constexpr (!HEAD)
        *(f4*)(x + (size_t)token * 96 + mf * 16 + lg * 4) = xc[i];
    }
  }

  // ---- tail LN on xc ----
  constexpr int ph = EMBED ? 0 : 1;
  {
    float s = 0.f, sq = 0.f;
#pragma unroll
    for (int i = 0; i < 2; ++i)
#pragma unroll
      for (int j = 0; j < 4; ++j) { s += xc[i][j]; sq += xc[i][j] * xc[i][j]; }
    s += __shfl_xor(s, 16); sq += __shfl_xor(sq, 16);
    s += __shfl_xor(s, 32); sq += __shfl_xor(sq, 32);
    if (lane < 16) { lnsh[ph][wave][lr][0] = s; lnsh[ph][wave][lr][1] = sq; }
  }
  // batch tail weights before the barrier (latency hides under the LN exchange)
  h4 wtreg[6][6];
  if (!HEAD || wave == 0) {
#pragma unroll
    for (int f = 0; f < 6; ++f) {
      const _Float16* wrow = HEAD
          ? (Wtail + (size_t)lr * 96 + lg * 4)
          : (Wtail + (size_t)((wave * 6 + f) * 16 + lr) * 96 + lg * 4);
#pragma unroll
      for (int st = 0; st < 6; ++st) wtreg[f][st] = *(const h4*)(wrow + st * 16);
      if constexpr (HEAD) break;
    }
  }
  __syncthreads();
  {
    float s = lnsh[ph][0][lr][0] + lnsh[ph][1][lr][0] + lnsh[ph][2][lr][0];
    float sq = lnsh[ph][0][lr][1] + lnsh[ph][1][lr][1] + lnsh[ph][2][lr][1];
    float mean = s * (1.f / 96.f);
    float rs = rsqrtf(sq * (1.f / 96.f) - mean * mean + 1e-5f);
#pragma unroll
    for (int i = 0; i < 2; ++i) {
      int cf = c0 + i;
      f4 g4 = *(const f4*)(lntg + cf * 16 + lg * 4);
      f4 b4 = *(const f4*)(lntb + cf * 16 + lg * 4);
      h4 xn;
#pragma unroll
      for (int j = 0; j < 4; ++j)
        xn[j] = (_Float16)((xc[i][j] - mean) * rs * g4[j] + b4[j]);
      *(h4*)&xsh[(cf * 16 + lr) * 16 + lg * 4] = xn;
    }
  }
  __syncthreads();
  h4 xf[6];
#pragma unroll
  for (int cf = 0; cf < 6; ++cf)
    xf[cf] = *(const h4*)&xsh[(cf * 16 + lr) * 16 + lg * 4];

  if constexpr (HEAD) {
    if (wave == 0) {
      f4 a = zero4;
#pragma unroll
      for (int st = 0; st < 6; ++st)
        a = MFMA16(wtreg[0][st], xf[st], a, 0, 0, 0);
      f4 bb = *(const f4*)(btail + lg * 4);
      f4 o;
#pragma unroll
      for (int j = 0; j < 4; ++j) o[j] = a[j] + bb[j];
      *(f4*)(out + (size_t)token * 16 + lg * 4) = o;
    }
  } else {
    // qkv: wave0 -> Q frags 0..5, wave1 -> K, wave2 -> V
#pragma unroll
    for (int f = 0; f < 6; ++f) {
      f4 a = zero4;
#pragma unroll
      for (int st = 0; st < 6; ++st)
        a = MFMA16(wtreg[f][st], xf[st], a, 0, 0, 0);
      if (wave < 2) {  // Q or K: [bh][t][16]
        _Float16* dst = (wave == 0 ? qh : kh) +
                        (size_t)(bidx * NH_ + f) * 16384 + (size_t)t * 16 + lg * 4;
        h4 hv = {(_Float16)a[0], (_Float16)a[1], (_Float16)a[2], (_Float16)a[3]};
        *(h4*)dst = hv;
      } else {         // V: [bh][d][1024]
        _Float16* dst = vt + (size_t)(bidx * NH_ + f) * 16384 + (size_t)(lg * 4) * 1024 + t;
#pragma unroll
        for (int r = 0; r < 4; ++r) dst[(size_t)r * 1024] = (_Float16)a[r];
      }
    }
  }
}

// ---------- MFMA f16 flash attention, fixed-max softmax, 16-row waves ------
__global__ __launch_bounds__(256, 6) void attn_mfma_kernel(
    const _Float16* __restrict__ Qh, const _Float16* __restrict__ Kh,
    const _Float16* __restrict__ Vt, _Float16* __restrict__ obh) {
  int bh = blockIdx.x;
  int wave = threadIdx.x >> 6;
  int lane = threadIdx.x & 63;
  int qt = wave * 16 + blockIdx.y;   // 0..63
  int q0 = qt * 16;
  int lr = lane & 15;
  int lg = lane >> 4;

  const _Float16* qb = Qh + (size_t)bh * 16384;
  const _Float16* kb = Kh + (size_t)bh * 16384;
  const _Float16* vb = Vt + (size_t)bh * 16384;

  h4 qf = *(const h4*)(qb + (size_t)(q0 + lr) * 16 + lg * 4);
  f4 O0 = {0.f, 0.f, 0.f, 0.f}, O1 = {0.f, 0.f, 0.f, 0.f};
  float lsum = 0.f;
  const f4 zero4 = {0.f, 0.f, 0.f, 0.f};

  int ntiles = qt / 2 + 1;
  h4 kc0, kc1, vc0, vc1, kn0, kn1, vn0, vn1;
  kc0 = *(const h4*)(kb + (size_t)lr * 16 + lg * 4);
  kc1 = *(const h4*)(kb + (size_t)(16 + lr) * 16 + lg * 4);
  vc0 = *(const h4*)(vb + (size_t)lr * 1024 + lg * 4);
  vc1 = *(const h4*)(vb + (size_t)lr * 1024 + 16 + lg * 4);

  for (int tt = 0; tt < ntiles; ++tt) {
    int s0 = tt * 32;
    bool last = (tt == ntiles - 1);
    if (!last) {
      int s1 = s0 + 32;
      kn0 = *(const h4*)(kb + (size_t)(s1 + lr) * 16 + lg * 4);
      kn1 = *(const h4*)(kb + (size_t)(s1 + 16 + lr) * 16 + lg * 4);
      vn0 = *(const h4*)(vb + (size_t)lr * 1024 + s1 + lg * 4);
      vn1 = *(const h4*)(vb + (size_t)lr * 1024 + s1 + 16 + lg * 4);
    }
    bool act1 = (s0 + 16 <= q0 + 15);
    f4 st0 = MFMA16(kc0, qf, zero4, 0, 0, 0);
    if (last) {
      int qi = q0 + lr;
#pragma unroll
      for (int r = 0; r < 4; ++r)
        if (s0 + lg * 4 + r > qi) st0[r] = -1e30f;
    }
    float p0[4];
#pragma unroll
    for (int r = 0; r < 4; ++r) {
      p0[r] = __builtin_amdgcn_exp2f(st0[r]);
      lsum += p0[r];
    }
    h4 pf0 = {(_Float16)p0[0], (_Float16)p0[1], (_Float16)p0[2], (_Float16)p0[3]};
    O0 = MFMA16(pf0, vc0, O0, 0, 0, 0);
    if (act1) {
      f4 st1 = MFMA16(kc1, qf, zero4, 0, 0, 0);
      if (last) {
        int qi = q0 + lr;
#pragma unroll
        for (int r = 0; r < 4; ++r)
          if (s0 + 16 + lg * 4 + r > qi) st1[r] = -1e30f;
      }
      float p1[4];
#pragma unroll
      for (int r = 0; r < 4; ++r) {
        p1[r] = __builtin_amdgcn_exp2f(st1[r]);
        lsum += p1[r];
      }
      h4 pf1 = {(_Float16)p1[0], (_Float16)p1[1], (_Float16)p1[2], (_Float16)p1[3]};
      O1 = MFMA16(pf1, vc1, O1, 0, 0, 0);
    }
    if (!last) { kc0 = kn0; kc1 = kn1; vc0 = vn0; vc1 = vn1; }
  }
  lsum += __shfl_xor(lsum, 16);
  lsum += __shfl_xor(lsum, 32);
  float linv = 1.f / lsum;
  int b = bh / NH_, h = bh % NH_;
#pragma unroll
  for (int r = 0; r < 4; ++r) {
    float li = __shfl(linv, lg * 4 + r);
    int q = q0 + lg * 4 + r;
    obh[(size_t)(b * 1024 + q) * 96 + h * 16 + lr] =
        (_Float16)((O0[r] + O1[r]) * li);
  }
}

extern "C" void kernel_launch(void* const* d_in, const int* in_sizes, int n_in,
                              void* d_out, int out_size, void* d_ws, size_t ws_size,
                              hipStream_t stream) {
  const float* goals   = (const float*)d_in[0];
  const float* obss    = (const float*)d_in[1];
  const float* w_go    = (const float*)d_in[2];
  const float* b_go    = (const float*)d_in[3];
  const float* pos_emb = (const float*)d_in[4];
  const float* wq      = (const float*)d_in[5];
  const float* wk      = (const float*)d_in[6];
  const float* wv      = (const float*)d_in[7];
  const float* w_proj  = (const float*)d_in[8];
  const float* b_proj  = (const float*)d_in[9];
  const float* ln1_g   = (const float*)d_in[10];
  const float* ln1_b   = (const float*)d_in[11];
  const float* ln2_g   = (const float*)d_in[12];
  const float* ln2_b   = (const float*)d_in[13];
  const float* w_ff1   = (const float*)d_in[14];
  const float* b_ff1   = (const float*)d_in[15];
  const float* w_ff2   = (const float*)d_in[16];
  const float* b_ff2   = (const float*)d_in[17];
  const float* lnf_g   = (const float*)d_in[18];
  const float* lnf_b   = (const float*)d_in[19];
  const float* w_act   = (const float*)d_in[20];
  const float* b_act   = (const float*)d_in[21];
  float* out = (float*)d_out;

  const int M = B_ * T_;  // 16384
  float* ws = (float*)d_ws;
  size_t off = 0;
  _Float16* P = (_Float16*)(ws + off); off += PACK_TOTAL / 2 + 64;
  float* x = ws + off; off += (size_t)M * 96;
  _Float16* obh = (_Float16*)(ws + off); off += (size_t)M * 48;
  _Float16* Qh = (_Float16*)(ws + off); off += (size_t)M * 48;
  _Float16* Kh = (_Float16*)(ws + off); off += (size_t)M * 48;
  _Float16* Vt = (_Float16*)(ws + off); off += (size_t)M * 48;

  pack_all_kernel<<<(PACK_TOTAL + 255) / 256, 256, 0, stream>>>(
      w_go, wq, wk, wv, w_proj, w_ff1, w_ff2, w_act, P);

  // embed + qkv(layer 0)
  stage_kernel<true, false><<<M / 16, 192, 0, stream>>>(
      goals, obss, pos_emb, b_go, nullptr, P + OFF_GO, nullptr, x,
      nullptr, nullptr, nullptr, nullptr, nullptr, nullptr,
      ln1_g, ln1_b, P + OFF_QKV, nullptr, Qh, Kh, Vt, nullptr);

  for (int l = 0; l < L_; ++l) {
    attn_mfma_kernel<<<dim3(B_ * NH_, 16), 256, 0, stream>>>(Qh, Kh, Vt, obh);
    if (l < L_ - 1) {
      stage_kernel<false, false><<<M / 16, 192, 0, stream>>>(
          nullptr, nullptr, nullptr, nullptr, obh,
          P + OFF_PROJ + (size_t)l * 9216, b_proj + l * 96, x,
          P + OFF_FF1 + (size_t)l * 36864, b_ff1 + l * 384,
          P + OFF_FF2 + (size_t)l * 36864, b_ff2 + l * 96,
          ln2_g + l * 96, ln2_b + l * 96,
          ln1_g + (l + 1) * 96, ln1_b + (l + 1) * 96,
          P + OFF_QKV + (size_t)(l + 1) * 27648, nullptr, Qh, Kh, Vt, nullptr);
    } else {
      stage_kernel<false, true><<<M / 16, 192, 0, stream>>>(
          nullptr, nullptr, nullptr, nullptr, obh,
          P + OFF_PROJ + (size_t)l * 9216, b_proj + l * 96, x,
          P + OFF_FF1 + (size_t)l * 36864, b_ff1 + l * 384,
          P + OFF_FF2 + (size_t)l * 36864, b_ff2 + l * 96,
          ln2_g + l * 96, ln2_b + l * 96,
          lnf_g, lnf_b, P + OFF_ACT, b_act, nullptr, nullptr, nullptr, out);
    }
  }
}

// Round 8
// 360.512 us; speedup vs baseline: 1.2749x; 1.2749x over previous
//
#include <hip/hip_runtime.h>
#include <math.h>

#define B_ 16
#define T_ 1024
#define D_ 96
#define L_ 6
#define NH_ 6
#define HS_ 16
#define FF_ 384

typedef _Float16 h4 __attribute__((ext_vector_type(4)));
typedef float f4 __attribute__((ext_vector_type(4)));

#define MFMA16 __builtin_amdgcn_mfma_f32_16x16x16f16

// packed f16 W^T buffer segment offsets (in halves)
#define OFF_GO   0
#define OFF_QKV  9216
#define OFF_PROJ 175104
#define OFF_FF1  230400
#define OFF_FF2  451584
#define OFF_ACT  672768
#define PACK_TOTAL 674304

// Q weights pre-scaled by 1/sqrt(16) * log2(e) so attn uses exp2 directly.
#define QSCALE 0.3606737602222409f

// ---------- pack all weights -> f16 W^T [N][K] ----------
__global__ __launch_bounds__(256) void pack_all_kernel(
    const float* __restrict__ w_go, const float* __restrict__ wq,
    const float* __restrict__ wk, const float* __restrict__ wv,
    const float* __restrict__ w_proj, const float* __restrict__ w_ff1,
    const float* __restrict__ w_ff2, const float* __restrict__ w_act,
    _Float16* __restrict__ P) {
  int i = blockIdx.x * 256 + threadIdx.x;
  if (i >= PACK_TOTAL) return;
  float v;
  if (i < OFF_QKV) {                       // w_go [96k][96n] -> [n][k]
    int o = i, n = o / 96, k = o % 96;
    v = w_go[k * 96 + n];
  } else if (i < OFF_PROJ) {               // wq/wk/wv -> [l][c=288][d=96]
    int o = i - OFF_QKV;
    int l = o / 27648, r = o % 27648, c = r / 96, d = r % 96;
    int which = c / 96;
    int hc = c % 96, h = hc >> 4, j = hc & 15;
    const float* s = (which == 0) ? wq : (which == 1 ? wk : wv);
    v = s[((l * NH_ + h) * 96 + d) * 16 + j];
    if (which == 0) v *= QSCALE;
  } else if (i < OFF_FF1) {                // w_proj [l][96k][96n] -> [l][n][k]
    int o = i - OFF_PROJ;
    int l = o / 9216, r = o % 9216, n = r / 96, k = r % 96;
    v = w_proj[l * 9216 + k * 96 + n];
  } else if (i < OFF_FF2) {                // w_ff1 [l][96k][384n] -> [l][n][k]
    int o = i - OFF_FF1;
    int l = o / 36864, r = o % 36864, n = r / 96, k = r % 96;
    v = w_ff1[l * 36864 + k * 384 + n];
  } else if (i < OFF_ACT) {                // w_ff2 [l][384k][96n] -> [l][n][k]
    int o = i - OFF_FF2;
    int l = o / 36864, r = o % 36864, n = r / 384, k = r % 384;
    v = w_ff2[l * 36864 + k * 96 + n];
  } else {                                 // w_act [96k][16n] -> [n][k]
    int o = i - OFF_ACT;
    int n = o / 96, k = o % 96;
    v = w_act[k * 16 + n];
  }
  P[i] = (_Float16)v;
}

// ---------- fused stage kernel: 3 waves x 2 token-groups (32 tokens) ------
// wave w owns col-frags {2w,2w+1}; ff1 hidden frags 8w..8w+7; tail frags
// 6w..6w+5 (w0=Q, w1=K, w2=V). Each weight frag loaded once, used for BOTH
// token groups (2 MFMAs per load) -> halves load chains per token.
template <bool EMBED, bool HEAD>
__global__ __launch_bounds__(192, 3) void stage_kernel(
    const float* __restrict__ goals, const float* __restrict__ obss,
    const float* __restrict__ pos, const float* __restrict__ b_go,
    const _Float16* __restrict__ obh, const _Float16* __restrict__ Wp,
    const float* __restrict__ bp, float* __restrict__ x,
    const _Float16* __restrict__ W1, const float* __restrict__ b1,
    const _Float16* __restrict__ W2, const float* __restrict__ b2,
    const float* __restrict__ ln2g, const float* __restrict__ ln2b,
    const float* __restrict__ lntg, const float* __restrict__ lntb,
    const _Float16* __restrict__ Wtail, const float* __restrict__ btail,
    _Float16* __restrict__ qh, _Float16* __restrict__ kh,
    _Float16* __restrict__ vt, float* __restrict__ out) {
  __shared__ _Float16 xsh[2][1536];       // [g][ (cf*16+row)*16 + col ]
  __shared__ float ysh[2][5760];          // [g][ ((wave*6+mf)*16+row)*20 + c ]
  __shared__ float lnsh[2][3][16][2];     // [g][wave][row][s,sq]
  const int tid = threadIdx.x;
  const int wave = tid / 64, lane = tid & 63;
  const int lr = lane & 15, lg = lane >> 4;
  const int row0 = blockIdx.x * 32;
  const int bidx = row0 >> 10;
  const int c0 = wave * 2;
  const f4 zero4 = {0.f, 0.f, 0.f, 0.f};
  const int tok0 = row0 + lr, tok1 = row0 + 16 + lr;
  const int tA = tok0 & 1023, tB = tok1 & 1023;

  f4 x1[2][2], xc[2][2];

  if constexpr (EMBED) {
    h4 ef[2][6];
#pragma unroll
    for (int g = 0; g < 2; ++g) {
      int t = g ? tB : tA;
#pragma unroll
      for (int st = 0; st < 6; ++st) {
        int k0 = st * 16 + lg * 4;
        f4 s4 = (st < 2)
            ? *(const f4*)(goals + bidx * 32 + k0)
            : *(const f4*)(obss + (size_t)(bidx * 1024 + t) * 64 + (k0 - 32));
        ef[g][st] = (h4){(_Float16)s4[0], (_Float16)s4[1],
                         (_Float16)s4[2], (_Float16)s4[3]};
      }
    }
#pragma unroll
    for (int i = 0; i < 2; ++i) {
      h4 wf[6];
      const _Float16* wrow = Wp + (size_t)((c0 + i) * 16 + lr) * 96 + lg * 4;
#pragma unroll
      for (int st = 0; st < 6; ++st) wf[st] = *(const h4*)(wrow + st * 16);
      f4 bb = *(const f4*)(b_go + (c0 + i) * 16 + lg * 4);
#pragma unroll
      for (int g = 0; g < 2; ++g) {
        int t = g ? tB : tA, tk = g ? tok1 : tok0;
        f4 a = zero4;
#pragma unroll
        for (int st = 0; st < 6; ++st) a = MFMA16(wf[st], ef[g][st], a, 0, 0, 0);
        f4 pp = *(const f4*)(pos + (size_t)t * 96 + (c0 + i) * 16 + lg * 4);
#pragma unroll
        for (int j = 0; j < 4; ++j) xc[g][i][j] = a[j] + bb[j] + pp[j];
        *(f4*)(x + (size_t)tk * 96 + (c0 + i) * 16 + lg * 4) = xc[g][i];
      }
    }
  } else {
    // ---- proj + resid ----
    h4 obf[2][6];
#pragma unroll
    for (int g = 0; g < 2; ++g) {
      const _Float16* orow = obh + (size_t)(g ? tok1 : tok0) * 96 + lg * 4;
#pragma unroll
      for (int st = 0; st < 6; ++st) obf[g][st] = *(const h4*)(orow + st * 16);
    }
#pragma unroll
    for (int i = 0; i < 2; ++i) {
      h4 wf[6];
      const _Float16* wrow = Wp + (size_t)((c0 + i) * 16 + lr) * 96 + lg * 4;
#pragma unroll
      for (int st = 0; st < 6; ++st) wf[st] = *(const h4*)(wrow + st * 16);
      f4 bb = *(const f4*)(bp + (c0 + i) * 16 + lg * 4);
#pragma unroll
      for (int g = 0; g < 2; ++g) {
        f4 a = zero4;
#pragma unroll
        for (int st = 0; st < 6; ++st) a = MFMA16(wf[st], obf[g][st], a, 0, 0, 0);
        f4 xr = *(const f4*)(x + (size_t)(g ? tok1 : tok0) * 96 + (c0 + i) * 16 + lg * 4);
#pragma unroll
        for (int j = 0; j < 4; ++j) x1[g][i][j] = a[j] + bb[j] + xr[j];
      }
    }
    // ---- LN2 ----
#pragma unroll
    for (int g = 0; g < 2; ++g) {
      float s = 0.f, sq = 0.f;
#pragma unroll
      for (int i = 0; i < 2; ++i)
#pragma unroll
        for (int j = 0; j < 4; ++j) { s += x1[g][i][j]; sq += x1[g][i][j] * x1[g][i][j]; }
      s += __shfl_xor(s, 16); sq += __shfl_xor(sq, 16);
      s += __shfl_xor(s, 32); sq += __shfl_xor(sq, 32);
      if (lane < 16) { lnsh[g][wave][lr][0] = s; lnsh[g][wave][lr][1] = sq; }
    }
    __syncthreads();
#pragma unroll
    for (int g = 0; g < 2; ++g) {
      float s = lnsh[g][0][lr][0] + lnsh[g][1][lr][0] + lnsh[g][2][lr][0];
      float sq = lnsh[g][0][lr][1] + lnsh[g][1][lr][1] + lnsh[g][2][lr][1];
      float mean = s * (1.f / 96.f);
      float rs = rsqrtf(sq * (1.f / 96.f) - mean * mean + 1e-5f);
#pragma unroll
      for (int i = 0; i < 2; ++i) {
        int cf = c0 + i;
        f4 g4 = *(const f4*)(ln2g + cf * 16 + lg * 4);
        f4 b4 = *(const f4*)(ln2b + cf * 16 + lg * 4);
        h4 xn;
#pragma unroll
        for (int j = 0; j < 4; ++j)
          xn[j] = (_Float16)((x1[g][i][j] - mean) * rs * g4[j] + b4[j]);
        *(h4*)&xsh[g][(cf * 16 + lr) * 16 + lg * 4] = xn;
      }
    }
    __syncthreads();
    h4 xnf[2][6];
#pragma unroll
    for (int g = 0; g < 2; ++g)
#pragma unroll
      for (int cf = 0; cf < 6; ++cf)
        xnf[g][cf] = *(const h4*)&xsh[g][(cf * 16 + lr) * 16 + lg * 4];

    // ---- ff1 + relu ----
    int nf0 = wave * 8;
    h4 hf[2][8];
#pragma unroll
    for (int f = 0; f < 8; ++f) {
      h4 wf[6];
      const _Float16* wrow = W1 + (size_t)((nf0 + f) * 16 + lr) * 96 + lg * 4;
#pragma unroll
      for (int st = 0; st < 6; ++st) wf[st] = *(const h4*)(wrow + st * 16);
      f4 b4 = *(const f4*)(b1 + (nf0 + f) * 16 + lg * 4);
#pragma unroll
      for (int g = 0; g < 2; ++g) {
        f4 h = zero4;
#pragma unroll
        for (int st = 0; st < 6; ++st) h = MFMA16(wf[st], xnf[g][st], h, 0, 0, 0);
#pragma unroll
        for (int j = 0; j < 4; ++j)
          hf[g][f][j] = (_Float16)fmaxf(h[j] + b4[j], 0.f);
      }
    }

    // ---- ff2: K-split partials, LDS reduce ----
    f4 yown[2][2];
#pragma unroll
    for (int mf = 0; mf < 6; ++mf) {
      h4 wf[8];
      const _Float16* wrow = W2 + (size_t)(mf * 16 + lr) * 384 + nf0 * 16 + lg * 4;
#pragma unroll
      for (int f = 0; f < 8; ++f) wf[f] = *(const h4*)(wrow + f * 16);
#pragma unroll
      for (int g = 0; g < 2; ++g) {
        f4 y = zero4;
#pragma unroll
        for (int f = 0; f < 8; ++f) y = MFMA16(wf[f], hf[g][f], y, 0, 0, 0);
        if ((mf >> 1) == wave) yown[g][mf & 1] = y;
        else *(f4*)&ysh[g][((wave * 6 + mf) * 16 + lr) * 20 + lg * 4] = y;
      }
    }
    __syncthreads();
#pragma unroll
    for (int i = 0; i < 2; ++i) {
      int mf = c0 + i;
      f4 b4 = *(const f4*)(b2 + mf * 16 + lg * 4);
#pragma unroll
      for (int g = 0; g < 2; ++g) {
        f4 tot = yown[g][i];
#pragma unroll
        for (int ow = 0; ow < 3; ++ow)
          if (ow != wave)
            tot += *(const f4*)&ysh[g][((ow * 6 + mf) * 16 + lr) * 20 + lg * 4];
#pragma unroll
        for (int j = 0; j < 4; ++j) xc[g][i][j] = x1[g][i][j] + tot[j] + b4[j];
        if constexpr (!HEAD)
          *(f4*)(x + (size_t)(g ? tok1 : tok0) * 96 + mf * 16 + lg * 4) = xc[g][i];
      }
    }
  }

  // ---- tail LN on xc ----
#pragma unroll
  for (int g = 0; g < 2; ++g) {
    float s = 0.f, sq = 0.f;
#pragma unroll
    for (int i = 0; i < 2; ++i)
#pragma unroll
      for (int j = 0; j < 4; ++j) { s += xc[g][i][j]; sq += xc[g][i][j] * xc[g][i][j]; }
    s += __shfl_xor(s, 16); sq += __shfl_xor(sq, 16);
    s += __shfl_xor(s, 32); sq += __shfl_xor(sq, 32);
    if (lane < 16) { lnsh[g][wave][lr][0] = s; lnsh[g][wave][lr][1] = sq; }
  }
  __syncthreads();
#pragma unroll
  for (int g = 0; g < 2; ++g) {
    float s = lnsh[g][0][lr][0] + lnsh[g][1][lr][0] + lnsh[g][2][lr][0];
    float sq = lnsh[g][0][lr][1] + lnsh[g][1][lr][1] + lnsh[g][2][lr][1];
    float mean = s * (1.f / 96.f);
    float rs = rsqrtf(sq * (1.f / 96.f) - mean * mean + 1e-5f);
#pragma unroll
    for (int i = 0; i < 2; ++i) {
      int cf = c0 + i;
      f4 g4 = *(const f4*)(lntg + cf * 16 + lg * 4);
      f4 b4 = *(const f4*)(lntb + cf * 16 + lg * 4);
      h4 xn;
#pragma unroll
      for (int j = 0; j < 4; ++j)
        xn[j] = (_Float16)((xc[g][i][j] - mean) * rs * g4[j] + b4[j]);
      *(h4*)&xsh[g][(cf * 16 + lr) * 16 + lg * 4] = xn;
    }
  }
  __syncthreads();
  h4 xf[2][6];
#pragma unroll
  for (int g = 0; g < 2; ++g)
#pragma unroll
    for (int cf = 0; cf < 6; ++cf)
      xf[g][cf] = *(const h4*)&xsh[g][(cf * 16 + lr) * 16 + lg * 4];

  if constexpr (HEAD) {
    if (wave == 0) {
      h4 wf[6];
      const _Float16* wrow = Wtail + (size_t)lr * 96 + lg * 4;
#pragma unroll
      for (int st = 0; st < 6; ++st) wf[st] = *(const h4*)(wrow + st * 16);
      f4 bb = *(const f4*)(btail + lg * 4);
#pragma unroll
      for (int g = 0; g < 2; ++g) {
        f4 a = zero4;
#pragma unroll
        for (int st = 0; st < 6; ++st) a = MFMA16(wf[st], xf[g][st], a, 0, 0, 0);
        f4 o;
#pragma unroll
        for (int j = 0; j < 4; ++j) o[j] = a[j] + bb[j];
        *(f4*)(out + (size_t)(g ? tok1 : tok0) * 16 + lg * 4) = o;
      }
    }
  } else {
    // qkv: wave0 -> Q frags 0..5, wave1 -> K, wave2 -> V
#pragma unroll
    for (int f = 0; f < 6; ++f) {
      h4 wf[6];
      const _Float16* wrow = Wtail + (size_t)((wave * 6 + f) * 16 + lr) * 96 + lg * 4;
#pragma unroll
      for (int st = 0; st < 6; ++st) wf[st] = *(const h4*)(wrow + st * 16);
#pragma unroll
      for (int g = 0; g < 2; ++g) {
        int t = g ? tB : tA;
        f4 a = zero4;
#pragma unroll
        for (int st = 0; st < 6; ++st) a = MFMA16(wf[st], xf[g][st], a, 0, 0, 0);
        if (wave < 2) {  // Q or K: [bh][t][16]
          _Float16* dst = (wave == 0 ? qh : kh) +
                          (size_t)(bidx * NH_ + f) * 16384 + (size_t)t * 16 + lg * 4;
          h4 hv = {(_Float16)a[0], (_Float16)a[1], (_Float16)a[2], (_Float16)a[3]};
          *(h4*)dst = hv;
        } else {         // V: [bh][d][1024]
          _Float16* dst = vt + (size_t)(bidx * NH_ + f) * 16384 + (size_t)(lg * 4) * 1024 + t;
#pragma unroll
          for (int r = 0; r < 4; ++r) dst[(size_t)r * 1024] = (_Float16)a[r];
        }
      }
    }
  }
}

// ---------- MFMA f16 flash attention, fixed-max softmax, 16-row waves ------
__global__ __launch_bounds__(256, 6) void attn_mfma_kernel(
    const _Float16* __restrict__ Qh, const _Float16* __restrict__ Kh,
    const _Float16* __restrict__ Vt, _Float16* __restrict__ obh) {
  int bh = blockIdx.x;
  int wave = threadIdx.x >> 6;
  int lane = threadIdx.x & 63;
  int qt = wave * 16 + blockIdx.y;   // 0..63
  int q0 = qt * 16;
  int lr = lane & 15;
  int lg = lane >> 4;

  const _Float16* qb = Qh + (size_t)bh * 16384;
  const _Float16* kb = Kh + (size_t)bh * 16384;
  const _Float16* vb = Vt + (size_t)bh * 16384;

  h4 qf = *(const h4*)(qb + (size_t)(q0 + lr) * 16 + lg * 4);
  f4 O0 = {0.f, 0.f, 0.f, 0.f}, O1 = {0.f, 0.f, 0.f, 0.f};
  float lsum = 0.f;
  const f4 zero4 = {0.f, 0.f, 0.f, 0.f};

  int ntiles = qt / 2 + 1;
  h4 kc0, kc1, vc0, vc1, kn0, kn1, vn0, vn1;
  kc0 = *(const h4*)(kb + (size_t)lr * 16 + lg * 4);
  kc1 = *(const h4*)(kb + (size_t)(16 + lr) * 16 + lg * 4);
  vc0 = *(const h4*)(vb + (size_t)lr * 1024 + lg * 4);
  vc1 = *(const h4*)(vb + (size_t)lr * 1024 + 16 + lg * 4);

  for (int tt = 0; tt < ntiles; ++tt) {
    int s0 = tt * 32;
    bool last = (tt == ntiles - 1);
    if (!last) {
      int s1 = s0 + 32;
      kn0 = *(const h4*)(kb + (size_t)(s1 + lr) * 16 + lg * 4);
      kn1 = *(const h4*)(kb + (size_t)(s1 + 16 + lr) * 16 + lg * 4);
      vn0 = *(const h4*)(vb + (size_t)lr * 1024 + s1 + lg * 4);
      vn1 = *(const h4*)(vb + (size_t)lr * 1024 + s1 + 16 + lg * 4);
    }
    bool act1 = (s0 + 16 <= q0 + 15);
    f4 st0 = MFMA16(kc0, qf, zero4, 0, 0, 0);
    if (last) {
      int qi = q0 + lr;
#pragma unroll
      for (int r = 0; r < 4; ++r)
        if (s0 + lg * 4 + r > qi) st0[r] = -1e30f;
    }
    float p0[4];
#pragma unroll
    for (int r = 0; r < 4; ++r) {
      p0[r] = __builtin_amdgcn_exp2f(st0[r]);
      lsum += p0[r];
    }
    h4 pf0 = {(_Float16)p0[0], (_Float16)p0[1], (_Float16)p0[2], (_Float16)p0[3]};
    O0 = MFMA16(pf0, vc0, O0, 0, 0, 0);
    if (act1) {
      f4 st1 = MFMA16(kc1, qf, zero4, 0, 0, 0);
      if (last) {
        int qi = q0 + lr;
#pragma unroll
        for (int r = 0; r < 4; ++r)
          if (s0 + 16 + lg * 4 + r > qi) st1[r] = -1e30f;
      }
      float p1[4];
#pragma unroll
      for (int r = 0; r < 4; ++r) {
        p1[r] = __builtin_amdgcn_exp2f(st1[r]);
        lsum += p1[r];
      }
      h4 pf1 = {(_Float16)p1[0], (_Float16)p1[1], (_Float16)p1[2], (_Float16)p1[3]};
      O1 = MFMA16(pf1, vc1, O1, 0, 0, 0);
    }
    if (!last) { kc0 = kn0; kc1 = kn1; vc0 = vn0; vc1 = vn1; }
  }
  lsum += __shfl_xor(lsum, 16);
  lsum += __shfl_xor(lsum, 32);
  float linv = 1.f / lsum;
  int b = bh / NH_, h = bh % NH_;
#pragma unroll
  for (int r = 0; r < 4; ++r) {
    float li = __shfl(linv, lg * 4 + r);
    int q = q0 + lg * 4 + r;
    obh[(size_t)(b * 1024 + q) * 96 + h * 16 + lr] =
        (_Float16)((O0[r] + O1[r]) * li);
  }
}

extern "C" void kernel_launch(void* const* d_in, const int* in_sizes, int n_in,
                              void* d_out, int out_size, void* d_ws, size_t ws_size,
                              hipStream_t stream) {
  const float* goals   = (const float*)d_in[0];
  const float* obss    = (const float*)d_in[1];
  const float* w_go    = (const float*)d_in[2];
  const float* b_go    = (const float*)d_in[3];
  const float* pos_emb = (const float*)d_in[4];
  const float* wq      = (const float*)d_in[5];
  const float* wk      = (const float*)d_in[6];
  const float* wv      = (const float*)d_in[7];
  const float* w_proj  = (const float*)d_in[8];
  const float* b_proj  = (const float*)d_in[9];
  const float* ln1_g   = (const float*)d_in[10];
  const float* ln1_b   = (const float*)d_in[11];
  const float* ln2_g   = (const float*)d_in[12];
  const float* ln2_b   = (const float*)d_in[13];
  const float* w_ff1   = (const float*)d_in[14];
  const float* b_ff1   = (const float*)d_in[15];
  const float* w_ff2   = (const float*)d_in[16];
  const float* b_ff2   = (const float*)d_in[17];
  const float* lnf_g   = (const float*)d_in[18];
  const float* lnf_b   = (const float*)d_in[19];
  const float* w_act   = (const float*)d_in[20];
  const float* b_act   = (const float*)d_in[21];
  float* out = (float*)d_out;

  const int M = B_ * T_;  // 16384
  float* ws = (float*)d_ws;
  size_t off = 0;
  _Float16* P = (_Float16*)(ws + off); off += PACK_TOTAL / 2 + 64;
  float* x = ws + off; off += (size_t)M * 96;
  _Float16* obh = (_Float16*)(ws + off); off += (size_t)M * 48;
  _Float16* Qh = (_Float16*)(ws + off); off += (size_t)M * 48;
  _Float16* Kh = (_Float16*)(ws + off); off += (size_t)M * 48;
  _Float16* Vt = (_Float16*)(ws + off); off += (size_t)M * 48;

  pack_all_kernel<<<(PACK_TOTAL + 255) / 256, 256, 0, stream>>>(
      w_go, wq, wk, wv, w_proj, w_ff1, w_ff2, w_act, P);

  // embed + qkv(layer 0)
  stage_kernel<true, false><<<M / 32, 192, 0, stream>>>(
      goals, obss, pos_emb, b_go, nullptr, P + OFF_GO, nullptr, x,
      nullptr, nullptr, nullptr, nullptr, nullptr, nullptr,
      ln1_g, ln1_b, P + OFF_QKV, nullptr, Qh, Kh, Vt, nullptr);

  for (int l = 0; l < L_; ++l) {
    attn_mfma_kernel<<<dim3(B_ * NH_, 16), 256, 0, stream>>>(Qh, Kh, Vt, obh);
    if (l < L_ - 1) {
      stage_kernel<false, false><<<M / 32, 192, 0, stream>>>(
          nullptr, nullptr, nullptr, nullptr, obh,
          P + OFF_PROJ + (size_t)l * 9216, b_proj + l * 96, x,
          P + OFF_FF1 + (size_t)l * 36864, b_ff1 + l * 384,
          P + OFF_FF2 + (size_t)l * 36864, b_ff2 + l * 96,
          ln2_g + l * 96, ln2_b + l * 96,
          ln1_g + (l + 1) * 96, ln1_b + (l + 1) * 96,
          P + OFF_QKV + (size_t)(l + 1) * 27648, nullptr, Qh, Kh, Vt, nullptr);
    } else {
      stage_kernel<false, true><<<M / 32, 192, 0, stream>>>(
          nullptr, nullptr, nullptr, nullptr, obh,
          P + OFF_PROJ + (size_t)l * 9216, b_proj + l * 96, x,
          P + OFF_FF1 + (size_t)l * 36864, b_ff1 + l * 384,
          P + OFF_FF2 + (size_t)l * 36864, b_ff2 + l * 96,
          ln2_g + l * 96, ln2_b + l * 96,
          lnf_g, lnf_b, P + OFF_ACT, b_act, nullptr, nullptr, nullptr, out);
    }
  }
}

// Round 9
// 340.614 us; speedup vs baseline: 1.3494x; 1.0584x over previous
//
#include <hip/hip_runtime.h>
#include <math.h>

#define B_ 16
#define T_ 1024
#define D_ 96
#define L_ 6
#define NH_ 6
#define HS_ 16
#define FF_ 384

typedef _Float16 h4 __attribute__((ext_vector_type(4)));
typedef float f4 __attribute__((ext_vector_type(4)));

#define MFMA16 __builtin_amdgcn_mfma_f32_16x16x16f16

// packed f16 W^T buffer segment offsets (in halves)
#define OFF_GO   0
#define OFF_QKV  9216
#define OFF_PROJ 175104
#define OFF_FF1  230400
#define OFF_FF2  451584
#define OFF_ACT  672768
#define PACK_TOTAL 674304

// Q weights pre-scaled by 1/sqrt(16) * log2(e) so attn uses exp2 directly.
#define QSCALE 0.3606737602222409f

// ---------- pack all weights -> f16 W^T [N][K] ----------
__global__ __launch_bounds__(256) void pack_all_kernel(
    const float* __restrict__ w_go, const float* __restrict__ wq,
    const float* __restrict__ wk, const float* __restrict__ wv,
    const float* __restrict__ w_proj, const float* __restrict__ w_ff1,
    const float* __restrict__ w_ff2, const float* __restrict__ w_act,
    _Float16* __restrict__ P) {
  int i = blockIdx.x * 256 + threadIdx.x;
  if (i >= PACK_TOTAL) return;
  float v;
  if (i < OFF_QKV) {                       // w_go [96k][96n] -> [n][k]
    int o = i, n = o / 96, k = o % 96;
    v = w_go[k * 96 + n];
  } else if (i < OFF_PROJ) {               // wq/wk/wv -> [l][c=288][d=96]
    int o = i - OFF_QKV;
    int l = o / 27648, r = o % 27648, c = r / 96, d = r % 96;
    int which = c / 96;
    int hc = c % 96, h = hc >> 4, j = hc & 15;
    const float* s = (which == 0) ? wq : (which == 1 ? wk : wv);
    v = s[((l * NH_ + h) * 96 + d) * 16 + j];
    if (which == 0) v *= QSCALE;
  } else if (i < OFF_FF1) {                // w_proj [l][96k][96n] -> [l][n][k]
    int o = i - OFF_PROJ;
    int l = o / 9216, r = o % 9216, n = r / 96, k = r % 96;
    v = w_proj[l * 9216 + k * 96 + n];
  } else if (i < OFF_FF2) {                // w_ff1 [l][96k][384n] -> [l][n][k]
    int o = i - OFF_FF1;
    int l = o / 36864, r = o % 36864, n = r / 96, k = r % 96;
    v = w_ff1[l * 36864 + k * 384 + n];
  } else if (i < OFF_ACT) {                // w_ff2 [l][384k][96n] -> [l][n][k]
    int o = i - OFF_FF2;
    int l = o / 36864, r = o % 36864, n = r / 384, k = r % 384;
    v = w_ff2[l * 36864 + k * 96 + n];
  } else {                                 // w_act [96k][16n] -> [n][k]
    int o = i - OFF_ACT;
    int n = o / 96, k = o % 96;
    v = w_act[k * 16 + n];
  }
  P[i] = (_Float16)v;
}

// ---------- fused stage kernel: 6 waves x 4 token-groups (64 tokens) ------
// wave w owns col-frag w (proj/LN/ff2-out/x-write), ff1 hidden frags 4w..4w+3,
// tail frags 3w..3w+2 (Q=0-5, K=6-11, V=12-17 -> w0,1=Q w2,3=K w4,5=V).
// ff2 via hf LDS exchange (full-K per wave). All LDS rows padded to 20 halves.
// LDS overlay: XSH (xn exchange, 15360B) shares region with HSH (hf, 61440B);
// LNS partials at 61440..64512. Barriers separate the overlapping uses.
template <bool EMBED, bool HEAD>
__global__ __launch_bounds__(384, 1) void stage_kernel(
    const float* __restrict__ goals, const float* __restrict__ obss,
    const float* __restrict__ pos, const float* __restrict__ b_go,
    const _Float16* __restrict__ obh, const _Float16* __restrict__ Wp,
    const float* __restrict__ bp, float* __restrict__ x,
    const _Float16* __restrict__ W1, const float* __restrict__ b1,
    const _Float16* __restrict__ W2, const float* __restrict__ b2,
    const float* __restrict__ ln2g, const float* __restrict__ ln2b,
    const float* __restrict__ lntg, const float* __restrict__ lntb,
    const _Float16* __restrict__ Wtail, const float* __restrict__ btail,
    _Float16* __restrict__ qh, _Float16* __restrict__ kh,
    _Float16* __restrict__ vt, float* __restrict__ out) {
  __shared__ float smemf[16128];  // 64512 B
#define XSH(g, row, c) ((_Float16*)smemf + (size_t)(g) * 1920 + (row) * 20 + (c))
#define HSH(g, f, r, c) ((_Float16*)smemf + (size_t)(g) * 7680 + ((f) * 16 + (r)) * 20 + (c))
#define LNS(g, w, r, i) smemf[15360 + (((g) * 6 + (w)) * 16 + (r)) * 2 + (i)]
  const int tid = threadIdx.x;
  const int wave = tid >> 6, lane = tid & 63;
  const int lr = lane & 15, lg = lane >> 4;
  const int row0 = blockIdx.x * 64;
  const int bidx = row0 >> 10;
  const int cfo = wave;  // owned col-frag 0..5
  const f4 zero4 = {0.f, 0.f, 0.f, 0.f};
  int tok[4], tt[4];
#pragma unroll
  for (int g = 0; g < 4; ++g) { tok[g] = row0 + g * 16 + lr; tt[g] = tok[g] & 1023; }

  f4 xc[4], x1[4];

  if constexpr (EMBED) {
    h4 ef[4][6];
#pragma unroll
    for (int st = 0; st < 2; ++st) {
      f4 s4 = *(const f4*)(goals + bidx * 32 + st * 16 + lg * 4);
      h4 e = (h4){(_Float16)s4[0], (_Float16)s4[1], (_Float16)s4[2], (_Float16)s4[3]};
#pragma unroll
      for (int g = 0; g < 4; ++g) ef[g][st] = e;
    }
#pragma unroll
    for (int g = 0; g < 4; ++g)
#pragma unroll
      for (int st = 2; st < 6; ++st) {
        f4 s4 = *(const f4*)(obss + (size_t)(bidx * 1024 + tt[g]) * 64 +
                             (st - 2) * 16 + lg * 4);
        ef[g][st] = (h4){(_Float16)s4[0], (_Float16)s4[1], (_Float16)s4[2], (_Float16)s4[3]};
      }
    h4 wf[6];
    const _Float16* wrow = Wp + (size_t)(cfo * 16 + lr) * 96 + lg * 4;
#pragma unroll
    for (int st = 0; st < 6; ++st) wf[st] = *(const h4*)(wrow + st * 16);
    f4 bb = *(const f4*)(b_go + cfo * 16 + lg * 4);
#pragma unroll
    for (int g = 0; g < 4; ++g) {
      f4 a = zero4;
#pragma unroll
      for (int st = 0; st < 6; ++st) a = MFMA16(wf[st], ef[g][st], a, 0, 0, 0);
      f4 pp = *(const f4*)(pos + (size_t)tt[g] * 96 + cfo * 16 + lg * 4);
#pragma unroll
      for (int j = 0; j < 4; ++j) xc[g][j] = a[j] + bb[j] + pp[j];
      *(f4*)(x + (size_t)tok[g] * 96 + cfo * 16 + lg * 4) = xc[g];
    }
  } else {
    // ---- proj + resid (own 1 col-frag, 4 groups) ----
    h4 obf[4][6];
#pragma unroll
    for (int g = 0; g < 4; ++g) {
      const _Float16* orow = obh + (size_t)tok[g] * 96 + lg * 4;
#pragma unroll
      for (int st = 0; st < 6; ++st) obf[g][st] = *(const h4*)(orow + st * 16);
    }
    h4 wf[6];
    const _Float16* wrow = Wp + (size_t)(cfo * 16 + lr) * 96 + lg * 4;
#pragma unroll
    for (int st = 0; st < 6; ++st) wf[st] = *(const h4*)(wrow + st * 16);
    f4 bb = *(const f4*)(bp + cfo * 16 + lg * 4);
#pragma unroll
    for (int g = 0; g < 4; ++g) {
      f4 a = zero4;
#pragma unroll
      for (int st = 0; st < 6; ++st) a = MFMA16(wf[st], obf[g][st], a, 0, 0, 0);
      f4 xr = *(const f4*)(x + (size_t)tok[g] * 96 + cfo * 16 + lg * 4);
#pragma unroll
      for (int j = 0; j < 4; ++j) x1[g][j] = a[j] + bb[j] + xr[j];
    }
    // ---- LN2 partials ----
#pragma unroll
    for (int g = 0; g < 4; ++g) {
      float s = x1[g][0] + x1[g][1] + x1[g][2] + x1[g][3];
      float sq = x1[g][0] * x1[g][0] + x1[g][1] * x1[g][1] +
                 x1[g][2] * x1[g][2] + x1[g][3] * x1[g][3];
      s += __shfl_xor(s, 16); sq += __shfl_xor(sq, 16);
      s += __shfl_xor(s, 32); sq += __shfl_xor(sq, 32);
      if (lane < 16) { LNS(g, wave, lr, 0) = s; LNS(g, wave, lr, 1) = sq; }
    }
    __syncthreads();  // B1
    {
      f4 g4 = *(const f4*)(ln2g + cfo * 16 + lg * 4);
      f4 b4 = *(const f4*)(ln2b + cfo * 16 + lg * 4);
#pragma unroll
      for (int g = 0; g < 4; ++g) {
        float s = 0.f, sq = 0.f;
#pragma unroll
        for (int w = 0; w < 6; ++w) { s += LNS(g, w, lr, 0); sq += LNS(g, w, lr, 1); }
        float mean = s * (1.f / 96.f);
        float rs = rsqrtf(sq * (1.f / 96.f) - mean * mean + 1e-5f);
        h4 xn;
#pragma unroll
        for (int j = 0; j < 4; ++j)
          xn[j] = (_Float16)((x1[g][j] - mean) * rs * g4[j] + b4[j]);
        *(h4*)XSH(g, cfo * 16 + lr, lg * 4) = xn;
      }
    }
    __syncthreads();  // B2
    h4 xnf[4][6];
#pragma unroll
    for (int g = 0; g < 4; ++g)
#pragma unroll
      for (int st = 0; st < 6; ++st)
        xnf[g][st] = *(const h4*)XSH(g, st * 16 + lr, lg * 4);
    __syncthreads();  // B2b (xn fully read before HSH overlays it)

    // ---- ff1 + relu -> HSH (own 4 hidden frags) ----
#pragma unroll
    for (int f = 0; f < 4; ++f) {
      int nf = wave * 4 + f;
      h4 w1f[6];
      const _Float16* wr = W1 + (size_t)(nf * 16 + lr) * 96 + lg * 4;
#pragma unroll
      for (int st = 0; st < 6; ++st) w1f[st] = *(const h4*)(wr + st * 16);
      f4 b4 = *(const f4*)(b1 + nf * 16 + lg * 4);
#pragma unroll
      for (int g = 0; g < 4; ++g) {
        f4 h = zero4;
#pragma unroll
        for (int st = 0; st < 6; ++st) h = MFMA16(w1f[st], xnf[g][st], h, 0, 0, 0);
        h4 hv;
#pragma unroll
        for (int j = 0; j < 4; ++j) hv[j] = (_Float16)fmaxf(h[j] + b4[j], 0.f);
        *(h4*)HSH(g, nf, lr, lg * 4) = hv;
      }
    }
    // ---- ff2 (own 1 output frag, full K=384 from HSH) ----
    h4 w2f[24];
    {
      const _Float16* wr = W2 + (size_t)(cfo * 16 + lr) * 384 + lg * 4;
#pragma unroll
      for (int f = 0; f < 24; ++f) w2f[f] = *(const h4*)(wr + f * 16);
    }
    __syncthreads();  // B3 (all hf written)
    {
      f4 b4 = *(const f4*)(b2 + cfo * 16 + lg * 4);
#pragma unroll
      for (int g = 0; g < 4; ++g) {
        f4 y = zero4;
#pragma unroll
        for (int f = 0; f < 24; ++f) {
          h4 hv = *(const h4*)HSH(g, f, lr, lg * 4);
          y = MFMA16(w2f[f], hv, y, 0, 0, 0);
        }
#pragma unroll
        for (int j = 0; j < 4; ++j) xc[g][j] = x1[g][j] + y[j] + b4[j];
        if constexpr (!HEAD)
          *(f4*)(x + (size_t)tok[g] * 96 + cfo * 16 + lg * 4) = xc[g];
      }
    }
  }

  // ---- tail LN on xc ----
#pragma unroll
  for (int g = 0; g < 4; ++g) {
    float s = xc[g][0] + xc[g][1] + xc[g][2] + xc[g][3];
    float sq = xc[g][0] * xc[g][0] + xc[g][1] * xc[g][1] +
               xc[g][2] * xc[g][2] + xc[g][3] * xc[g][3];
    s += __shfl_xor(s, 16); sq += __shfl_xor(sq, 16);
    s += __shfl_xor(s, 32); sq += __shfl_xor(sq, 32);
    if (lane < 16) { LNS(g, wave, lr, 0) = s; LNS(g, wave, lr, 1) = sq; }
  }
  __syncthreads();  // B4 (also: all HSH reads done before XSH overlays)
  {
    f4 g4 = *(const f4*)(lntg + cfo * 16 + lg * 4);
    f4 b4 = *(const f4*)(lntb + cfo * 16 + lg * 4);
#pragma unroll
    for (int g = 0; g < 4; ++g) {
      float s = 0.f, sq = 0.f;
#pragma unroll
      for (int w = 0; w < 6; ++w) { s += LNS(g, w, lr, 0); sq += LNS(g, w, lr, 1); }
      float mean = s * (1.f / 96.f);
      float rs = rsqrtf(sq * (1.f / 96.f) - mean * mean + 1e-5f);
      h4 xn;
#pragma unroll
      for (int j = 0; j < 4; ++j)
        xn[j] = (_Float16)((xc[g][j] - mean) * rs * g4[j] + b4[j]);
      *(h4*)XSH(g, cfo * 16 + lr, lg * 4) = xn;
    }
  }
  __syncthreads();  // B5
  if constexpr (HEAD) {
    if (wave == 0) {
      h4 wt[6];
      const _Float16* wr = Wtail + (size_t)lr * 96 + lg * 4;
#pragma unroll
      for (int st = 0; st < 6; ++st) wt[st] = *(const h4*)(wr + st * 16);
      f4 bb = *(const f4*)(btail + lg * 4);
#pragma unroll
      for (int g = 0; g < 4; ++g) {
        f4 a = zero4;
#pragma unroll
        for (int st = 0; st < 6; ++st) {
          h4 xf = *(const h4*)XSH(g, st * 16 + lr, lg * 4);
          a = MFMA16(wt[st], xf, a, 0, 0, 0);
        }
        f4 o;
#pragma unroll
        for (int j = 0; j < 4; ++j) o[j] = a[j] + bb[j];
        *(f4*)(out + (size_t)tok[g] * 16 + lg * 4) = o;
      }
    }
  } else {
    h4 xf[4][6];
#pragma unroll
    for (int g = 0; g < 4; ++g)
#pragma unroll
      for (int st = 0; st < 6; ++st)
        xf[g][st] = *(const h4*)XSH(g, st * 16 + lr, lg * 4);
    // tail frags: nf = wave*3 + f; Q:0-5 K:6-11 V:12-17
#pragma unroll
    for (int f = 0; f < 3; ++f) {
      int nf = wave * 3 + f;
      h4 wt[6];
      const _Float16* wr = Wtail + (size_t)(nf * 16 + lr) * 96 + lg * 4;
#pragma unroll
      for (int st = 0; st < 6; ++st) wt[st] = *(const h4*)(wr + st * 16);
#pragma unroll
      for (int g = 0; g < 4; ++g) {
        f4 a = zero4;
#pragma unroll
        for (int st = 0; st < 6; ++st) a = MFMA16(wt[st], xf[g][st], a, 0, 0, 0);
        if (nf < 12) {  // Q or K: [bh][t][16]
          int h = nf < 6 ? nf : nf - 6;
          _Float16* dst = (nf < 6 ? qh : kh) +
                          (size_t)(bidx * NH_ + h) * 16384 + (size_t)tt[g] * 16 + lg * 4;
          h4 hv = {(_Float16)a[0], (_Float16)a[1], (_Float16)a[2], (_Float16)a[3]};
          *(h4*)dst = hv;
        } else {        // V: [bh][d][1024]
          _Float16* dst = vt + (size_t)(bidx * NH_ + (nf - 12)) * 16384 +
                          (size_t)(lg * 4) * 1024 + tt[g];
#pragma unroll
          for (int r = 0; r < 4; ++r) dst[(size_t)r * 1024] = (_Float16)a[r];
        }
      }
    }
  }
#undef XSH
#undef HSH
#undef LNS
}

// ---------- MFMA f16 flash attention, fixed-max softmax, 16-row waves ------
__global__ __launch_bounds__(256, 6) void attn_mfma_kernel(
    const _Float16* __restrict__ Qh, const _Float16* __restrict__ Kh,
    const _Float16* __restrict__ Vt, _Float16* __restrict__ obh) {
  int bh = blockIdx.x;
  int wave = threadIdx.x >> 6;
  int lane = threadIdx.x & 63;
  int qt = wave * 16 + blockIdx.y;   // 0..63
  int q0 = qt * 16;
  int lr = lane & 15;
  int lg = lane >> 4;

  const _Float16* qb = Qh + (size_t)bh * 16384;
  const _Float16* kb = Kh + (size_t)bh * 16384;
  const _Float16* vb = Vt + (size_t)bh * 16384;

  h4 qf = *(const h4*)(qb + (size_t)(q0 + lr) * 16 + lg * 4);
  f4 O0 = {0.f, 0.f, 0.f, 0.f}, O1 = {0.f, 0.f, 0.f, 0.f};
  float lsum = 0.f;
  const f4 zero4 = {0.f, 0.f, 0.f, 0.f};

  int ntiles = qt / 2 + 1;
  h4 kc0, kc1, vc0, vc1, kn0, kn1, vn0, vn1;
  kc0 = *(const h4*)(kb + (size_t)lr * 16 + lg * 4);
  kc1 = *(const h4*)(kb + (size_t)(16 + lr) * 16 + lg * 4);
  vc0 = *(const h4*)(vb + (size_t)lr * 1024 + lg * 4);
  vc1 = *(const h4*)(vb + (size_t)lr * 1024 + 16 + lg * 4);

  for (int tt = 0; tt < ntiles; ++tt) {
    int s0 = tt * 32;
    bool last = (tt == ntiles - 1);
    if (!last) {
      int s1 = s0 + 32;
      kn0 = *(const h4*)(kb + (size_t)(s1 + lr) * 16 + lg * 4);
      kn1 = *(const h4*)(kb + (size_t)(s1 + 16 + lr) * 16 + lg * 4);
      vn0 = *(const h4*)(vb + (size_t)lr * 1024 + s1 + lg * 4);
      vn1 = *(const h4*)(vb + (size_t)lr * 1024 + s1 + 16 + lg * 4);
    }
    bool act1 = (s0 + 16 <= q0 + 15);
    f4 st0 = MFMA16(kc0, qf, zero4, 0, 0, 0);
    if (last) {
      int qi = q0 + lr;
#pragma unroll
      for (int r = 0; r < 4; ++r)
        if (s0 + lg * 4 + r > qi) st0[r] = -1e30f;
    }
    float p0[4];
#pragma unroll
    for (int r = 0; r < 4; ++r) {
      p0[r] = __builtin_amdgcn_exp2f(st0[r]);
      lsum += p0[r];
    }
    h4 pf0 = {(_Float16)p0[0], (_Float16)p0[1], (_Float16)p0[2], (_Float16)p0[3]};
    O0 = MFMA16(pf0, vc0, O0, 0, 0, 0);
    if (act1) {
      f4 st1 = MFMA16(kc1, qf, zero4, 0, 0, 0);
      if (last) {
        int qi = q0 + lr;
#pragma unroll
        for (int r = 0; r < 4; ++r)
          if (s0 + 16 + lg * 4 + r > qi) st1[r] = -1e30f;
      }
      float p1[4];
#pragma unroll
      for (int r = 0; r < 4; ++r) {
        p1[r] = __builtin_amdgcn_exp2f(st1[r]);
        lsum += p1[r];
      }
      h4 pf1 = {(_Float16)p1[0], (_Float16)p1[1], (_Float16)p1[2], (_Float16)p1[3]};
      O1 = MFMA16(pf1, vc1, O1, 0, 0, 0);
    }
    if (!last) { kc0 = kn0; kc1 = kn1; vc0 = vn0; vc1 = vn1; }
  }
  lsum += __shfl_xor(lsum, 16);
  lsum += __shfl_xor(lsum, 32);
  float linv = 1.f / lsum;
  int b = bh / NH_, h = bh % NH_;
#pragma unroll
  for (int r = 0; r < 4; ++r) {
    float li = __shfl(linv, lg * 4 + r);
    int q = q0 + lg * 4 + r;
    obh[(size_t)(b * 1024 + q) * 96 + h * 16 + lr] =
        (_Float16)((O0[r] + O1[r]) * li);
  }
}

extern "C" void kernel_launch(void* const* d_in, const int* in_sizes, int n_in,
                              void* d_out, int out_size, void* d_ws, size_t ws_size,
                              hipStream_t stream) {
  const float* goals   = (const float*)d_in[0];
  const float* obss    = (const float*)d_in[1];
  const float* w_go    = (const float*)d_in[2];
  const float* b_go    = (const float*)d_in[3];
  const float* pos_emb = (const float*)d_in[4];
  const float* wq      = (const float*)d_in[5];
  const float* wk      = (const float*)d_in[6];
  const float* wv      = (const float*)d_in[7];
  const float* w_proj  = (const float*)d_in[8];
  const float* b_proj  = (const float*)d_in[9];
  const float* ln1_g   = (const float*)d_in[10];
  const float* ln1_b   = (const float*)d_in[11];
  const float* ln2_g   = (const float*)d_in[12];
  const float* ln2_b   = (const float*)d_in[13];
  const float* w_ff1   = (const float*)d_in[14];
  const float* b_ff1   = (const float*)d_in[15];
  const float* w_ff2   = (const float*)d_in[16];
  const float* b_ff2   = (const float*)d_in[17];
  const float* lnf_g   = (const float*)d_in[18];
  const float* lnf_b   = (const float*)d_in[19];
  const float* w_act   = (const float*)d_in[20];
  const float* b_act   = (const float*)d_in[21];
  float* out = (float*)d_out;

  const int M = B_ * T_;  // 16384
  float* ws = (float*)d_ws;
  size_t off = 0;
  _Float16* P = (_Float16*)(ws + off); off += PACK_TOTAL / 2 + 64;
  float* x = ws + off; off += (size_t)M * 96;
  _Float16* obh = (_Float16*)(ws + off); off += (size_t)M * 48;
  _Float16* Qh = (_Float16*)(ws + off); off += (size_t)M * 48;
  _Float16* Kh = (_Float16*)(ws + off); off += (size_t)M * 48;
  _Float16* Vt = (_Float16*)(ws + off); off += (size_t)M * 48;

  pack_all_kernel<<<(PACK_TOTAL + 255) / 256, 256, 0, stream>>>(
      w_go, wq, wk, wv, w_proj, w_ff1, w_ff2, w_act, P);

  // embed + qkv(layer 0)
  stage_kernel<true, false><<<M / 64, 384, 0, stream>>>(
      goals, obss, pos_emb, b_go, nullptr, P + OFF_GO, nullptr, x,
      nullptr, nullptr, nullptr, nullptr, nullptr, nullptr,
      ln1_g, ln1_b, P + OFF_QKV, nullptr, Qh, Kh, Vt, nullptr);

  for (int l = 0; l < L_; ++l) {
    attn_mfma_kernel<<<dim3(B_ * NH_, 16), 256, 0, stream>>>(Qh, Kh, Vt, obh);
    if (l < L_ - 1) {
      stage_kernel<false, false><<<M / 64, 384, 0, stream>>>(
          nullptr, nullptr, nullptr, nullptr, obh,
          P + OFF_PROJ + (size_t)l * 9216, b_proj + l * 96, x,
          P + OFF_FF1 + (size_t)l * 36864, b_ff1 + l * 384,
          P + OFF_FF2 + (size_t)l * 36864, b_ff2 + l * 96,
          ln2_g + l * 96, ln2_b + l * 96,
          ln1_g + (l + 1) * 96, ln1_b + (l + 1) * 96,
          P + OFF_QKV + (size_t)(l + 1) * 27648, nullptr, Qh, Kh, Vt, nullptr);
    } else {
      stage_kernel<false, true><<<M / 64, 384, 0, stream>>>(
          nullptr, nullptr, nullptr, nullptr, obh,
          P + OFF_PROJ + (size_t)l * 9216, b_proj + l * 96, x,
          P + OFF_FF1 + (size_t)l * 36864, b_ff1 + l * 384,
          P + OFF_FF2 + (size_t)l * 36864, b_ff2 + l * 96,
          ln2_g + l * 96, ln2_b + l * 96,
          lnf_g, lnf_b, P + OFF_ACT, b_act, nullptr, nullptr, nullptr, out);
    }
  }
}

// Round 10
// 261.693 us; speedup vs baseline: 1.7563x; 1.3016x over previous
//
#include <hip/hip_runtime.h>
#include <math.h>

#define B_ 16
#define T_ 1024
#define D_ 96
#define L_ 6
#define NH_ 6
#define HS_ 16
#define FF_ 384

typedef _Float16 h4 __attribute__((ext_vector_type(4)));
typedef float f4 __attribute__((ext_vector_type(4)));

#define MFMA16 __builtin_amdgcn_mfma_f32_16x16x16f16

// packed f16 W^T buffer segment offsets (in halves)
#define OFF_GO   0
#define OFF_QKV  9216
#define OFF_PROJ 175104
#define OFF_FF1  230400
#define OFF_FF2  451584
#define OFF_ACT  672768
#define PACK_TOTAL 674304

// Q weights pre-scaled by 1/sqrt(16) * log2(e) so attn uses exp2 directly.
#define QSCALE 0.3606737602222409f

// ---------- pack all weights -> f16 W^T [N][K] ----------
__global__ __launch_bounds__(256) void pack_all_kernel(
    const float* __restrict__ w_go, const float* __restrict__ wq,
    const float* __restrict__ wk, const float* __restrict__ wv,
    const float* __restrict__ w_proj, const float* __restrict__ w_ff1,
    const float* __restrict__ w_ff2, const float* __restrict__ w_act,
    _Float16* __restrict__ P) {
  int i = blockIdx.x * 256 + threadIdx.x;
  if (i >= PACK_TOTAL) return;
  float v;
  if (i < OFF_QKV) {                       // w_go [96k][96n] -> [n][k]
    int o = i, n = o / 96, k = o % 96;
    v = w_go[k * 96 + n];
  } else if (i < OFF_PROJ) {               // wq/wk/wv -> [l][c=288][d=96]
    int o = i - OFF_QKV;
    int l = o / 27648, r = o % 27648, c = r / 96, d = r % 96;
    int which = c / 96;
    int hc = c % 96, h = hc >> 4, j = hc & 15;
    const float* s = (which == 0) ? wq : (which == 1 ? wk : wv);
    v = s[((l * NH_ + h) * 96 + d) * 16 + j];
    if (which == 0) v *= QSCALE;
  } else if (i < OFF_FF1) {                // w_proj [l][96k][96n] -> [l][n][k]
    int o = i - OFF_PROJ;
    int l = o / 9216, r = o % 9216, n = r / 96, k = r % 96;
    v = w_proj[l * 9216 + k * 96 + n];
  } else if (i < OFF_FF2) {                // w_ff1 [l][96k][384n] -> [l][n][k]
    int o = i - OFF_FF1;
    int l = o / 36864, r = o % 36864, n = r / 96, k = r % 96;
    v = w_ff1[l * 36864 + k * 384 + n];
  } else if (i < OFF_ACT) {                // w_ff2 [l][384k][96n] -> [l][n][k]
    int o = i - OFF_FF2;
    int l = o / 36864, r = o % 36864, n = r / 384, k = r % 384;
    v = w_ff2[l * 36864 + k * 96 + n];
  } else {                                 // w_act [96k][16n] -> [n][k]
    int o = i - OFF_ACT;
    int n = o / 96, k = o % 96;
    v = w_act[k * 16 + n];
  }
  P[i] = (_Float16)v;
}

// ---------- fused stage kernel: 6 waves x 4 token-groups (64 tokens) ------
template <bool EMBED, bool HEAD>
__global__ __launch_bounds__(384, 1) void stage_kernel(
    const float* __restrict__ goals, const float* __restrict__ obss,
    const float* __restrict__ pos, const float* __restrict__ b_go,
    const _Float16* __restrict__ obh, const _Float16* __restrict__ Wp,
    const float* __restrict__ bp, float* __restrict__ x,
    const _Float16* __restrict__ W1, const float* __restrict__ b1,
    const _Float16* __restrict__ W2, const float* __restrict__ b2,
    const float* __restrict__ ln2g, const float* __restrict__ ln2b,
    const float* __restrict__ lntg, const float* __restrict__ lntb,
    const _Float16* __restrict__ Wtail, const float* __restrict__ btail,
    _Float16* __restrict__ qh, _Float16* __restrict__ kh,
    _Float16* __restrict__ vt, float* __restrict__ out) {
  __shared__ float smemf[16128];  // 64512 B
#define XSH(g, row, c) ((_Float16*)smemf + (size_t)(g) * 1920 + (row) * 20 + (c))
#define HSH(g, f, r, c) ((_Float16*)smemf + (size_t)(g) * 7680 + ((f) * 16 + (r)) * 20 + (c))
#define LNS(g, w, r, i) smemf[15360 + (((g) * 6 + (w)) * 16 + (r)) * 2 + (i)]
  const int tid = threadIdx.x;
  const int wave = tid >> 6, lane = tid & 63;
  const int lr = lane & 15, lg = lane >> 4;
  const int row0 = blockIdx.x * 64;
  const int bidx = row0 >> 10;
  const int cfo = wave;  // owned col-frag 0..5
  const f4 zero4 = {0.f, 0.f, 0.f, 0.f};
  int tok[4], tt[4];
#pragma unroll
  for (int g = 0; g < 4; ++g) { tok[g] = row0 + g * 16 + lr; tt[g] = tok[g] & 1023; }

  f4 xc[4], x1[4];

  if constexpr (EMBED) {
    h4 ef[4][6];
#pragma unroll
    for (int st = 0; st < 2; ++st) {
      f4 s4 = *(const f4*)(goals + bidx * 32 + st * 16 + lg * 4);
      h4 e = (h4){(_Float16)s4[0], (_Float16)s4[1], (_Float16)s4[2], (_Float16)s4[3]};
#pragma unroll
      for (int g = 0; g < 4; ++g) ef[g][st] = e;
    }
#pragma unroll
    for (int g = 0; g < 4; ++g)
#pragma unroll
      for (int st = 2; st < 6; ++st) {
        f4 s4 = *(const f4*)(obss + (size_t)(bidx * 1024 + tt[g]) * 64 +
                             (st - 2) * 16 + lg * 4);
        ef[g][st] = (h4){(_Float16)s4[0], (_Float16)s4[1], (_Float16)s4[2], (_Float16)s4[3]};
      }
    h4 wf[6];
    const _Float16* wrow = Wp + (size_t)(cfo * 16 + lr) * 96 + lg * 4;
#pragma unroll
    for (int st = 0; st < 6; ++st) wf[st] = *(const h4*)(wrow + st * 16);
    f4 bb = *(const f4*)(b_go + cfo * 16 + lg * 4);
#pragma unroll
    for (int g = 0; g < 4; ++g) {
      f4 a = zero4;
#pragma unroll
      for (int st = 0; st < 6; ++st) a = MFMA16(wf[st], ef[g][st], a, 0, 0, 0);
      f4 pp = *(const f4*)(pos + (size_t)tt[g] * 96 + cfo * 16 + lg * 4);
#pragma unroll
      for (int j = 0; j < 4; ++j) xc[g][j] = a[j] + bb[j] + pp[j];
      *(f4*)(x + (size_t)tok[g] * 96 + cfo * 16 + lg * 4) = xc[g];
    }
  } else {
    // ---- proj + resid (own 1 col-frag, 4 groups) ----
    h4 obf[4][6];
#pragma unroll
    for (int g = 0; g < 4; ++g) {
      const _Float16* orow = obh + (size_t)tok[g] * 96 + lg * 4;
#pragma unroll
      for (int st = 0; st < 6; ++st) obf[g][st] = *(const h4*)(orow + st * 16);
    }
    h4 wf[6];
    const _Float16* wrow = Wp + (size_t)(cfo * 16 + lr) * 96 + lg * 4;
#pragma unroll
    for (int st = 0; st < 6; ++st) wf[st] = *(const h4*)(wrow + st * 16);
    f4 bb = *(const f4*)(bp + cfo * 16 + lg * 4);
#pragma unroll
    for (int g = 0; g < 4; ++g) {
      f4 a = zero4;
#pragma unroll
      for (int st = 0; st < 6; ++st) a = MFMA16(wf[st], obf[g][st], a, 0, 0, 0);
      f4 xr = *(const f4*)(x + (size_t)tok[g] * 96 + cfo * 16 + lg * 4);
#pragma unroll
      for (int j = 0; j < 4; ++j) x1[g][j] = a[j] + bb[j] + xr[j];
    }
    // ---- LN2 partials ----
#pragma unroll
    for (int g = 0; g < 4; ++g) {
      float s = x1[g][0] + x1[g][1] + x1[g][2] + x1[g][3];
      float sq = x1[g][0] * x1[g][0] + x1[g][1] * x1[g][1] +
                 x1[g][2] * x1[g][2] + x1[g][3] * x1[g][3];
      s += __shfl_xor(s, 16); sq += __shfl_xor(sq, 16);
      s += __shfl_xor(s, 32); sq += __shfl_xor(sq, 32);
      if (lane < 16) { LNS(g, wave, lr, 0) = s; LNS(g, wave, lr, 1) = sq; }
    }
    __syncthreads();  // B1
    {
      f4 g4 = *(const f4*)(ln2g + cfo * 16 + lg * 4);
      f4 b4 = *(const f4*)(ln2b + cfo * 16 + lg * 4);
#pragma unroll
      for (int g = 0; g < 4; ++g) {
        float s = 0.f, sq = 0.f;
#pragma unroll
        for (int w = 0; w < 6; ++w) { s += LNS(g, w, lr, 0); sq += LNS(g, w, lr, 1); }
        float mean = s * (1.f / 96.f);
        float rs = rsqrtf(sq * (1.f / 96.f) - mean * mean + 1e-5f);
        h4 xn;
#pragma unroll
        for (int j = 0; j < 4; ++j)
          xn[j] = (_Float16)((x1[g][j] - mean) * rs * g4[j] + b4[j]);
        *(h4*)XSH(g, cfo * 16 + lr, lg * 4) = xn;
      }
    }
    __syncthreads();  // B2
    h4 xnf[4][6];
#pragma unroll
    for (int g = 0; g < 4; ++g)
#pragma unroll
      for (int st = 0; st < 6; ++st)
        xnf[g][st] = *(const h4*)XSH(g, st * 16 + lr, lg * 4);
    __syncthreads();  // B2b (xn fully read before HSH overlays it)

    // ---- ff1 + relu -> HSH (own 4 hidden frags) ----
#pragma unroll
    for (int f = 0; f < 4; ++f) {
      int nf = wave * 4 + f;
      h4 w1f[6];
      const _Float16* wr = W1 + (size_t)(nf * 16 + lr) * 96 + lg * 4;
#pragma unroll
      for (int st = 0; st < 6; ++st) w1f[st] = *(const h4*)(wr + st * 16);
      f4 b4 = *(const f4*)(b1 + nf * 16 + lg * 4);
#pragma unroll
      for (int g = 0; g < 4; ++g) {
        f4 h = zero4;
#pragma unroll
        for (int st = 0; st < 6; ++st) h = MFMA16(w1f[st], xnf[g][st], h, 0, 0, 0);
        h4 hv;
#pragma unroll
        for (int j = 0; j < 4; ++j) hv[j] = (_Float16)fmaxf(h[j] + b4[j], 0.f);
        *(h4*)HSH(g, nf, lr, lg * 4) = hv;
      }
    }
    // ---- ff2 (own 1 output frag, full K=384 from HSH) ----
    h4 w2f[24];
    {
      const _Float16* wr = W2 + (size_t)(cfo * 16 + lr) * 384 + lg * 4;
#pragma unroll
      for (int f = 0; f < 24; ++f) w2f[f] = *(const h4*)(wr + f * 16);
    }
    __syncthreads();  // B3 (all hf written)
    {
      f4 b4 = *(const f4*)(b2 + cfo * 16 + lg * 4);
#pragma unroll
      for (int g = 0; g < 4; ++g) {
        f4 y = zero4;
#pragma unroll
        for (int f = 0; f < 24; ++f) {
          h4 hv = *(const h4*)HSH(g, f, lr, lg * 4);
          y = MFMA16(w2f[f], hv, y, 0, 0, 0);
        }
#pragma unroll
        for (int j = 0; j < 4; ++j) xc[g][j] = x1[g][j] + y[j] + b4[j];
        if constexpr (!HEAD)
          *(f4*)(x + (size_t)tok[g] * 96 + cfo * 16 + lg * 4) = xc[g];
      }
    }
  }

  // ---- tail LN on xc ----
#pragma unroll
  for (int g = 0; g < 4; ++g) {
    float s = xc[g][0] + xc[g][1] + xc[g][2] + xc[g][3];
    float sq = xc[g][0] * xc[g][0] + xc[g][1] * xc[g][1] +
               xc[g][2] * xc[g][2] + xc[g][3] * xc[g][3];
    s += __shfl_xor(s, 16); sq += __shfl_xor(sq, 16);
    s += __shfl_xor(s, 32); sq += __shfl_xor(sq, 32);
    if (lane < 16) { LNS(g, wave, lr, 0) = s; LNS(g, wave, lr, 1) = sq; }
  }
  __syncthreads();  // B4 (also: all HSH reads done before XSH overlays)
  {
    f4 g4 = *(const f4*)(lntg + cfo * 16 + lg * 4);
    f4 b4 = *(const f4*)(lntb + cfo * 16 + lg * 4);
#pragma unroll
    for (int g = 0; g < 4; ++g) {
      float s = 0.f, sq = 0.f;
#pragma unroll
      for (int w = 0; w < 6; ++w) { s += LNS(g, w, lr, 0); sq += LNS(g, w, lr, 1); }
      float mean = s * (1.f / 96.f);
      float rs = rsqrtf(sq * (1.f / 96.f) - mean * mean + 1e-5f);
      h4 xn;
#pragma unroll
      for (int j = 0; j < 4; ++j)
        xn[j] = (_Float16)((xc[g][j] - mean) * rs * g4[j] + b4[j]);
      *(h4*)XSH(g, cfo * 16 + lr, lg * 4) = xn;
    }
  }
  __syncthreads();  // B5
  if constexpr (HEAD) {
    if (wave == 0) {
      h4 wt[6];
      const _Float16* wr = Wtail + (size_t)lr * 96 + lg * 4;
#pragma unroll
      for (int st = 0; st < 6; ++st) wt[st] = *(const h4*)(wr + st * 16);
      f4 bb = *(const f4*)(btail + lg * 4);
#pragma unroll
      for (int g = 0; g < 4; ++g) {
        f4 a = zero4;
#pragma unroll
        for (int st = 0; st < 6; ++st) {
          h4 xf = *(const h4*)XSH(g, st * 16 + lr, lg * 4);
          a = MFMA16(wt[st], xf, a, 0, 0, 0);
        }
        f4 o;
#pragma unroll
        for (int j = 0; j < 4; ++j) o[j] = a[j] + bb[j];
        *(f4*)(out + (size_t)tok[g] * 16 + lg * 4) = o;
      }
    }
  } else {
    h4 xf[4][6];
#pragma unroll
    for (int g = 0; g < 4; ++g)
#pragma unroll
      for (int st = 0; st < 6; ++st)
        xf[g][st] = *(const h4*)XSH(g, st * 16 + lr, lg * 4);
    // tail frags: nf = wave*3 + f; Q:0-5 K:6-11 V:12-17
#pragma unroll
    for (int f = 0; f < 3; ++f) {
      int nf = wave * 3 + f;
      h4 wt[6];
      const _Float16* wr = Wtail + (size_t)(nf * 16 + lr) * 96 + lg * 4;
#pragma unroll
      for (int st = 0; st < 6; ++st) wt[st] = *(const h4*)(wr + st * 16);
#pragma unroll
      for (int g = 0; g < 4; ++g) {
        f4 a = zero4;
#pragma unroll
        for (int st = 0; st < 6; ++st) a = MFMA16(wt[st], xf[g][st], a, 0, 0, 0);
        if (nf < 12) {  // Q or K: [bh][t][16]
          int h = nf < 6 ? nf : nf - 6;
          _Float16* dst = (nf < 6 ? qh : kh) +
                          (size_t)(bidx * NH_ + h) * 16384 + (size_t)tt[g] * 16 + lg * 4;
          h4 hv = {(_Float16)a[0], (_Float16)a[1], (_Float16)a[2], (_Float16)a[3]};
          *(h4*)dst = hv;
        } else {        // V: [bh][d][1024]
          _Float16* dst = vt + (size_t)(bidx * NH_ + (nf - 12)) * 16384 +
                          (size_t)(lg * 4) * 1024 + tt[g];
#pragma unroll
          for (int r = 0; r < 4; ++r) dst[(size_t)r * 1024] = (_Float16)a[r];
        }
      }
    }
  }
#undef XSH
#undef HSH
#undef LNS
}

// ---------- MFMA f16 flash attention: 32 q-rows/wave, fixed-max softmax ----
// grid (96 bh, 8); wave qb = wave*8 + by in [0,32); each wave: rows
// [qb*32, qb*32+32) as two 16-row subtiles sharing every K/V tile load.
// Hot loop (tiles fully below the diagonal) is mask/branch-free; last
// tile peeled with causal masking.
__global__ __launch_bounds__(256, 6) void attn_mfma_kernel(
    const _Float16* __restrict__ Qh, const _Float16* __restrict__ Kh,
    const _Float16* __restrict__ Vt, _Float16* __restrict__ obh) {
  int bh = blockIdx.x;
  int wave = threadIdx.x >> 6;
  int lane = threadIdx.x & 63;
  int qb = wave * 8 + blockIdx.y;    // 0..31
  int q0 = qb * 32;
  int lr = lane & 15;
  int lg = lane >> 4;

  const _Float16* qp = Qh + (size_t)bh * 16384;
  const _Float16* kb = Kh + (size_t)bh * 16384;
  const _Float16* vb = Vt + (size_t)bh * 16384;

  h4 qf0 = *(const h4*)(qp + (size_t)(q0 + lr) * 16 + lg * 4);
  h4 qf1 = *(const h4*)(qp + (size_t)(q0 + 16 + lr) * 16 + lg * 4);
  f4 O0 = {0.f, 0.f, 0.f, 0.f}, O1 = {0.f, 0.f, 0.f, 0.f};
  float ls0 = 0.f, ls1 = 0.f;
  const f4 zero4 = {0.f, 0.f, 0.f, 0.f};

  h4 kc0, kc1, vc0, vc1, kn0, kn1, vn0, vn1;
  kc0 = *(const h4*)(kb + (size_t)lr * 16 + lg * 4);
  kc1 = *(const h4*)(kb + (size_t)(16 + lr) * 16 + lg * 4);
  vc0 = *(const h4*)(vb + (size_t)lr * 1024 + lg * 4);
  vc1 = *(const h4*)(vb + (size_t)lr * 1024 + 16 + lg * 4);

  // hot loop: tiles [0, q0), no masking needed
  for (int tt = 0; tt < qb; ++tt) {
    int s1 = tt * 32 + 32;
    kn0 = *(const h4*)(kb + (size_t)(s1 + lr) * 16 + lg * 4);
    kn1 = *(const h4*)(kb + (size_t)(s1 + 16 + lr) * 16 + lg * 4);
    vn0 = *(const h4*)(vb + (size_t)lr * 1024 + s1 + lg * 4);
    vn1 = *(const h4*)(vb + (size_t)lr * 1024 + s1 + 16 + lg * 4);

    f4 sa0 = MFMA16(kc0, qf0, zero4, 0, 0, 0);
    f4 sa1 = MFMA16(kc1, qf0, zero4, 0, 0, 0);
    f4 sb0 = MFMA16(kc0, qf1, zero4, 0, 0, 0);
    f4 sb1 = MFMA16(kc1, qf1, zero4, 0, 0, 0);
    float pa0[4], pa1[4], pb0[4], pb1[4];
#pragma unroll
    for (int r = 0; r < 4; ++r) {
      pa0[r] = __builtin_amdgcn_exp2f(sa0[r]);
      pa1[r] = __builtin_amdgcn_exp2f(sa1[r]);
      pb0[r] = __builtin_amdgcn_exp2f(sb0[r]);
      pb1[r] = __builtin_amdgcn_exp2f(sb1[r]);
      ls0 += pa0[r] + pa1[r];
      ls1 += pb0[r] + pb1[r];
    }
    h4 fa0 = {(_Float16)pa0[0], (_Float16)pa0[1], (_Float16)pa0[2], (_Float16)pa0[3]};
    h4 fa1 = {(_Float16)pa1[0], (_Float16)pa1[1], (_Float16)pa1[2], (_Float16)pa1[3]};
    h4 fb0 = {(_Float16)pb0[0], (_Float16)pb0[1], (_Float16)pb0[2], (_Float16)pb0[3]};
    h4 fb1 = {(_Float16)pb1[0], (_Float16)pb1[1], (_Float16)pb1[2], (_Float16)pb1[3]};
    O0 = MFMA16(fa0, vc0, O0, 0, 0, 0);
    O0 = MFMA16(fa1, vc1, O0, 0, 0, 0);
    O1 = MFMA16(fb0, vc0, O1, 0, 0, 0);
    O1 = MFMA16(fb1, vc1, O1, 0, 0, 0);
    kc0 = kn0; kc1 = kn1; vc0 = vn0; vc1 = vn1;
  }

  // last tile [q0, q0+32): u0 sees kv[q0,q0+16) masked; u1 sees kv[q0,q0+16)
  // in full plus kv[q0+16,q0+32) masked. mask: local s = lg*4+r vs row lr.
  {
    // u = 0 (rows q0+lr), kv half 0 masked
    f4 sa0 = MFMA16(kc0, qf0, zero4, 0, 0, 0);
    float pa0[4];
#pragma unroll
    for (int r = 0; r < 4; ++r) {
      pa0[r] = (lg * 4 + r <= lr) ? __builtin_amdgcn_exp2f(sa0[r]) : 0.f;
      ls0 += pa0[r];
    }
    h4 fa0 = {(_Float16)pa0[0], (_Float16)pa0[1], (_Float16)pa0[2], (_Float16)pa0[3]};
    O0 = MFMA16(fa0, vc0, O0, 0, 0, 0);
    // u = 1 (rows q0+16+lr): kv half 0 full, kv half 1 masked
    f4 sb0 = MFMA16(kc0, qf1, zero4, 0, 0, 0);
    f4 sb1 = MFMA16(kc1, qf1, zero4, 0, 0, 0);
    float pb0[4], pb1[4];
#pragma unroll
    for (int r = 0; r < 4; ++r) {
      pb0[r] = __builtin_amdgcn_exp2f(sb0[r]);
      pb1[r] = (lg * 4 + r <= lr) ? __builtin_amdgcn_exp2f(sb1[r]) : 0.f;
      ls1 += pb0[r] + pb1[r];
    }
    h4 fb0 = {(_Float16)pb0[0], (_Float16)pb0[1], (_Float16)pb0[2], (_Float16)pb0[3]};
    h4 fb1 = {(_Float16)pb1[0], (_Float16)pb1[1], (_Float16)pb1[2], (_Float16)pb1[3]};
    O1 = MFMA16(fb0, vc0, O1, 0, 0, 0);
    O1 = MFMA16(fb1, vc1, O1, 0, 0, 0);
  }

  ls0 += __shfl_xor(ls0, 16); ls0 += __shfl_xor(ls0, 32);
  ls1 += __shfl_xor(ls1, 16); ls1 += __shfl_xor(ls1, 32);
  float li0 = 1.f / ls0, li1 = 1.f / ls1;
  int b = bh / NH_, h = bh % NH_;
#pragma unroll
  for (int r = 0; r < 4; ++r) {
    float l0 = __shfl(li0, lg * 4 + r);
    float l1 = __shfl(li1, lg * 4 + r);
    int qa = q0 + lg * 4 + r;
    obh[(size_t)(b * 1024 + qa) * 96 + h * 16 + lr] = (_Float16)(O0[r] * l0);
    obh[(size_t)(b * 1024 + qa + 16) * 96 + h * 16 + lr] = (_Float16)(O1[r] * l1);
  }
}

extern "C" void kernel_launch(void* const* d_in, const int* in_sizes, int n_in,
                              void* d_out, int out_size, void* d_ws, size_t ws_size,
                              hipStream_t stream) {
  const float* goals   = (const float*)d_in[0];
  const float* obss    = (const float*)d_in[1];
  const float* w_go    = (const float*)d_in[2];
  const float* b_go    = (const float*)d_in[3];
  const float* pos_emb = (const float*)d_in[4];
  const float* wq      = (const float*)d_in[5];
  const float* wk      = (const float*)d_in[6];
  const float* wv      = (const float*)d_in[7];
  const float* w_proj  = (const float*)d_in[8];
  const float* b_proj  = (const float*)d_in[9];
  const float* ln1_g   = (const float*)d_in[10];
  const float* ln1_b   = (const float*)d_in[11];
  const float* ln2_g   = (const float*)d_in[12];
  const float* ln2_b   = (const float*)d_in[13];
  const float* w_ff1   = (const float*)d_in[14];
  const float* b_ff1   = (const float*)d_in[15];
  const float* w_ff2   = (const float*)d_in[16];
  const float* b_ff2   = (const float*)d_in[17];
  const float* lnf_g   = (const float*)d_in[18];
  const float* lnf_b   = (const float*)d_in[19];
  const float* w_act   = (const float*)d_in[20];
  const float* b_act   = (const float*)d_in[21];
  float* out = (float*)d_out;

  const int M = B_ * T_;  // 16384
  float* ws = (float*)d_ws;
  size_t off = 0;
  _Float16* P = (_Float16*)(ws + off); off += PACK_TOTAL / 2 + 64;
  float* x = ws + off; off += (size_t)M * 96;
  _Float16* obh = (_Float16*)(ws + off); off += (size_t)M * 48;
  _Float16* Qh = (_Float16*)(ws + off); off += (size_t)M * 48;
  _Float16* Kh = (_Float16*)(ws + off); off += (size_t)M * 48;
  _Float16* Vt = (_Float16*)(ws + off); off += (size_t)M * 48;

  pack_all_kernel<<<(PACK_TOTAL + 255) / 256, 256, 0, stream>>>(
      w_go, wq, wk, wv, w_proj, w_ff1, w_ff2, w_act, P);

  // embed + qkv(layer 0)
  stage_kernel<true, false><<<M / 64, 384, 0, stream>>>(
      goals, obss, pos_emb, b_go, nullptr, P + OFF_GO, nullptr, x,
      nullptr, nullptr, nullptr, nullptr, nullptr, nullptr,
      ln1_g, ln1_b, P + OFF_QKV, nullptr, Qh, Kh, Vt, nullptr);

  for (int l = 0; l < L_; ++l) {
    attn_mfma_kernel<<<dim3(B_ * NH_, 8), 256, 0, stream>>>(Qh, Kh, Vt, obh);
    if (l < L_ - 1) {
      stage_kernel<false, false><<<M / 64, 384, 0, stream>>>(
          nullptr, nullptr, nullptr, nullptr, obh,
          P + OFF_PROJ + (size_t)l * 9216, b_proj + l * 96, x,
          P + OFF_FF1 + (size_t)l * 36864, b_ff1 + l * 384,
          P + OFF_FF2 + (size_t)l * 36864, b_ff2 + l * 96,
          ln2_g + l * 96, ln2_b + l * 96,
          ln1_g + (l + 1) * 96, ln1_b + (l + 1) * 96,
          P + OFF_QKV + (size_t)(l + 1) * 27648, nullptr, Qh, Kh, Vt, nullptr);
    } else {
      stage_kernel<false, true><<<M / 64, 384, 0, stream>>>(
          nullptr, nullptr, nullptr, nullptr, obh,
          P + OFF_PROJ + (size_t)l * 9216, b_proj + l * 96, x,
          P + OFF_FF1 + (size_t)l * 36864, b_ff1 + l * 384,
          P + OFF_FF2 + (size_t)l * 36864, b_ff2 + l * 96,
          ln2_g + l * 96, ln2_b + l * 96,
          lnf_g, lnf_b, P + OFF_ACT, b_act, nullptr, nullptr, nullptr, out);
    }
  }
}